// Round 1
// baseline (5981.868 us; speedup 1.0000x reference)
//
#include <hip/hip_runtime.h>
#include <hip/hip_bf16.h>
#include <math.h>

#define B_ 128
#define S_ 2048
#define D_IN_ 512
#define D_MODEL_ 2048
#define M_ 25
#define NSY_ 64
#define H_ 8
#define T_ 10
#define REP_ 2080
#define DH_ 64

// ---------------------------------------------------------------------------
// Generic tiled f32 GEMM: C[M,N] = A[M,K] @ B[K,N] + bias[N]
// BM=128, BN=32, BK=32; 256 threads; 8x2 micro-tile.
// Requires M%128==0, N%32==0, K%32==0, lda%4==0, N%4==0.
// ---------------------------------------------------------------------------
#define BM 128
#define BN 32
#define BK 32

__global__ __launch_bounds__(256) void gemm_f32(
    const float* __restrict__ A, int lda,
    const float* __restrict__ Bm, // ldb == N
    const float* __restrict__ bias,
    float* __restrict__ C, int ldc,
    int M, int N, int K)
{
    const int nb = blockIdx.x, mb = blockIdx.y;
    __shared__ float As[BK][BM + 4];
    __shared__ float Bs[BK][BN + 4];
    const int tid = threadIdx.x;
    const int tm = tid >> 4;   // 0..15 -> 8 rows each
    const int tn = tid & 15;   // 0..15 -> 2 cols each
    float acc[8][2] = {};
    const float* Ablk = A + (size_t)mb * BM * lda;
    const float* Bblk = Bm + (size_t)nb * BN;

    for (int k0 = 0; k0 < K; k0 += BK) {
        // A tile: 128 x 32, float4 per thread x4 passes, store transposed
        {
            const int r0 = tid >> 3;          // 0..31
            const int c4 = (tid & 7) * 4;     // 0..28
            #pragma unroll
            for (int i = 0; i < 4; i++) {
                const int m = r0 + 32 * i;
                float4 v = *(const float4*)(Ablk + (size_t)m * lda + k0 + c4);
                As[c4 + 0][m] = v.x; As[c4 + 1][m] = v.y;
                As[c4 + 2][m] = v.z; As[c4 + 3][m] = v.w;
            }
            // B tile: 32 x 32, one float4 per thread
            const int kr = tid >> 3;
            float4 v = *(const float4*)(Bblk + (size_t)(k0 + kr) * N + (tid & 7) * 4);
            *(float4*)&Bs[kr][(tid & 7) * 4] = v;
        }
        __syncthreads();
        #pragma unroll
        for (int kk = 0; kk < BK; kk++) {
            float4 a0 = *(const float4*)&As[kk][tm * 8];
            float4 a1 = *(const float4*)&As[kk][tm * 8 + 4];
            float2 bb = *(const float2*)&Bs[kk][tn * 2];
            float av[8] = {a0.x, a0.y, a0.z, a0.w, a1.x, a1.y, a1.z, a1.w};
            #pragma unroll
            for (int r = 0; r < 8; r++) {
                acc[r][0] += av[r] * bb.x;
                acc[r][1] += av[r] * bb.y;
            }
        }
        __syncthreads();
    }
    #pragma unroll
    for (int r = 0; r < 8; r++) {
        const int m = mb * BM + tm * 8 + r;
        const int n = nb * BN + tn * 2;
        C[(size_t)m * ldc + n]     = acc[r][0] + bias[n];
        C[(size_t)m * ldc + n + 1] = acc[r][1] + bias[n + 1];
    }
}

// ---------------------------------------------------------------------------
// feats2[c,s,k] = emb[c,k] + (-sin(th))*W_pos[0,k] + cos(th)*W_pos[1,k] + b_pos[k]
// th = pi * s / (S-1)
// ---------------------------------------------------------------------------
__global__ void feats_kernel(const float* __restrict__ emb,
                             const float* __restrict__ Wp,
                             const float* __restrict__ bp,
                             float* __restrict__ f2)
{
    const int gid = blockIdx.x * 256 + threadIdx.x; // 2*S*512
    const int k = gid & 511;
    const int s = (gid >> 9) & (S_ - 1);
    const int c = gid >> 20;
    const float th = 3.14159265358979323846f * (float)s / (float)(S_ - 1);
    f2[gid] = emb[c * 512 + k] + (-sinf(th)) * Wp[k] + cosf(th) * Wp[512 + k] + bp[k];
}

// ---------------------------------------------------------------------------
// init act + cat[:,512:2560] from start_act
// ---------------------------------------------------------------------------
__global__ void init_act_kernel(const float* __restrict__ sa,
                                float* __restrict__ act,
                                float* __restrict__ cat)
{
    const int gid = blockIdx.x * 256 + threadIdx.x; // B*2048
    const int b = gid >> 11, n = gid & 2047;
    const float v = sa[n];
    act[gid] = v;
    cat[(size_t)b * 2560 + 512 + n] = v;
}

__global__ void init_trace_kernel(const float* __restrict__ st,
                                  float* __restrict__ trace)
{
    const int gid = blockIdx.x * 256 + threadIdx.x; // B*2048*25
    trace[gid] = st[gid % (D_MODEL_ * M_)];
}

// ---------------------------------------------------------------------------
// sync: s_out[b,p] = alpha/sqrt(beta); alpha state kept; beta recomputed
// ---------------------------------------------------------------------------
__global__ void sync_kernel(const float* __restrict__ act,
                            float* __restrict__ alpha,
                            const float* __restrict__ decay,
                            const int t, const int off,
                            float* __restrict__ sout)
{
    const int b = blockIdx.x;
    const int p = blockIdx.y * 256 + threadIdx.x;
    if (p >= REP_) return;
    int i = 0, rem = p;
    while (rem >= NSY_ - i) { rem -= NSY_ - i; i++; }
    const int j = i + rem;
    const float si = act[(size_t)b * D_MODEL_ + off + i];
    const float sj = act[(size_t)b * D_MODEL_ + off + j];
    const float pair = si * sj;
    const float r = expf(-decay[p]);
    float a;
    if (t == 0) a = pair;
    else        a = r * alpha[(size_t)b * REP_ + p] + pair;
    alpha[(size_t)b * REP_ + p] = a;
    float bta = 1.f;
    for (int k = 0; k < t; k++) bta = r * bta + 1.f;
    sout[(size_t)b * REP_ + p] = a / sqrtf(bta);
}

// ---------------------------------------------------------------------------
// attention per (b,h): scores -> softmax -> weighted V sum
// ---------------------------------------------------------------------------
__global__ __launch_bounds__(256) void attn_kernel(
    const float* __restrict__ q,      // (B,512)
    const float* __restrict__ Ktab,   // (2,S,512)
    const float* __restrict__ Vtab,   // (2,S,512)
    const int*   __restrict__ tokens, // (B,S)
    float* __restrict__ o)            // (B,512)
{
    const int bh = blockIdx.x;
    const int b = bh >> 3, h = bh & 7;
    __shared__ float qs[64];
    __shared__ float sc[S_];
    __shared__ float red[256];
    __shared__ float po[4][64];
    const int tid = threadIdx.x;
    if (tid < 64) qs[tid] = q[(size_t)b * 512 + h * 64 + tid];
    __syncthreads();

    const int* trow = tokens + (size_t)b * S_;
    float lmax = -1e30f;
    #pragma unroll
    for (int i = 0; i < 8; i++) {
        const int s = tid + i * 256;
        const int tok = trow[s];
        const float4* kv = (const float4*)(Ktab + ((size_t)(tok * S_ + s)) * 512 + h * 64);
        float acc = 0.f;
        #pragma unroll
        for (int d4 = 0; d4 < 16; d4++) {
            float4 k4 = kv[d4];
            acc += qs[d4*4+0]*k4.x + qs[d4*4+1]*k4.y + qs[d4*4+2]*k4.z + qs[d4*4+3]*k4.w;
        }
        acc *= 0.125f; // 1/sqrt(64)
        sc[s] = acc;
        lmax = fmaxf(lmax, acc);
    }
    red[tid] = lmax; __syncthreads();
    for (int off = 128; off > 0; off >>= 1) {
        if (tid < off) red[tid] = fmaxf(red[tid], red[tid + off]);
        __syncthreads();
    }
    const float mx = red[0];
    __syncthreads();

    float lsum = 0.f;
    #pragma unroll
    for (int i = 0; i < 8; i++) {
        const int s = tid + i * 256;
        const float e = expf(sc[s] - mx);
        sc[s] = e;
        lsum += e;
    }
    red[tid] = lsum; __syncthreads();
    for (int off = 128; off > 0; off >>= 1) {
        if (tid < off) red[tid] += red[tid + off];
        __syncthreads();
    }
    const float inv = 1.f / red[0];

    const int d = tid & 63, grp = tid >> 6;
    float acc = 0.f;
    const int s0 = grp * 512;
    for (int s = s0; s < s0 + 512; s++) {
        const int tok = trow[s];
        acc += sc[s] * Vtab[((size_t)(tok * S_ + s)) * 512 + h * 64 + d];
    }
    po[grp][d] = acc; __syncthreads();
    if (tid < 64) {
        o[(size_t)b * 512 + h * 64 + tid] =
            (po[0][tid] + po[1][tid] + po[2][tid] + po[3][tid]) * inv;
    }
}

// ---------------------------------------------------------------------------
// state = LN(g1 * sigmoid(g2)) over D_MODEL
// ---------------------------------------------------------------------------
__global__ __launch_bounds__(256) void glu_ln_kernel(
    const float* __restrict__ pre,   // (B,4096)
    const float* __restrict__ g,
    const float* __restrict__ bta,
    float* __restrict__ state)       // (B,2048)
{
    const int b = blockIdx.x;
    const int tid = threadIdx.x;
    __shared__ float v[D_MODEL_];
    __shared__ float r1[256], r2[256];
    float s1 = 0.f, s2 = 0.f;
    #pragma unroll
    for (int i = 0; i < 8; i++) {
        const int dd = tid + i * 256;
        const float g1 = pre[(size_t)b * 4096 + dd];
        const float g2 = pre[(size_t)b * 4096 + 2048 + dd];
        const float val = g1 * (1.f / (1.f + expf(-g2)));
        v[dd] = val; s1 += val; s2 += val * val;
    }
    r1[tid] = s1; r2[tid] = s2; __syncthreads();
    for (int off = 128; off > 0; off >>= 1) {
        if (tid < off) { r1[tid] += r1[tid + off]; r2[tid] += r2[tid + off]; }
        __syncthreads();
    }
    const float mu = r1[0] * (1.f / D_MODEL_);
    const float var = fmaxf(r2[0] * (1.f / D_MODEL_) - mu * mu, 0.f);
    const float inv = 1.f / sqrtf(var + 1e-5f);
    #pragma unroll
    for (int i = 0; i < 8; i++) {
        const int dd = tid + i * 256;
        state[(size_t)b * D_MODEL_ + dd] = (v[dd] - mu) * inv * g[dd] + bta[dd];
    }
}

// ---------------------------------------------------------------------------
// trace shift + LN over M + y = xn @ Wn + bn; act = y0*sigmoid(y1)/temp
// one thread per (b,n), in-place trace update
// ---------------------------------------------------------------------------
__global__ void trace_kernel(float* __restrict__ trace,      // (B,2048,25)
                             const float* __restrict__ state,// (B,2048)
                             const float* __restrict__ ln_g, // (25)
                             const float* __restrict__ ln_b, // (25)
                             const float* __restrict__ Wn,   // (25,2,2048)
                             const float* __restrict__ bn,   // (2048,2)
                             const float* __restrict__ temp, // (1)
                             float* __restrict__ act,        // (B,2048)
                             float* __restrict__ cat)        // (B,2560)
{
    const int gid = blockIdx.x * 256 + threadIdx.x; // B*2048
    const int b = gid >> 11, n = gid & 2047;
    float* tr = trace + (size_t)gid * M_;
    float x[M_];
    #pragma unroll
    for (int m = 0; m < M_ - 1; m++) x[m] = tr[m + 1];
    x[M_ - 1] = state[gid];
    #pragma unroll
    for (int m = 0; m < M_; m++) tr[m] = x[m];
    float s1 = 0.f, s2 = 0.f;
    #pragma unroll
    for (int m = 0; m < M_; m++) { s1 += x[m]; s2 += x[m] * x[m]; }
    const float mu = s1 * (1.f / M_);
    const float var = fmaxf(s2 * (1.f / M_) - mu * mu, 0.f);
    const float inv = 1.f / sqrtf(var + 1e-5f);
    float y0 = bn[n * 2 + 0], y1 = bn[n * 2 + 1];
    #pragma unroll
    for (int m = 0; m < M_; m++) {
        const float xn = (x[m] - mu) * inv * ln_g[m] + ln_b[m];
        y0 += xn * Wn[(size_t)(m * 2 + 0) * D_MODEL_ + n];
        y1 += xn * Wn[(size_t)(m * 2 + 1) * D_MODEL_ + n];
    }
    const float a = y0 * (1.f / (1.f + expf(-y1))) / temp[0];
    act[gid] = a;
    cat[(size_t)b * 2560 + 512 + n] = a;
}

// ---------------------------------------------------------------------------
// write preds (strided by T) + entropy certs
// ---------------------------------------------------------------------------
__global__ __launch_bounds__(256) void out_kernel(
    const float* __restrict__ pred,  // (B,4096)
    float* __restrict__ dout,
    const int t)
{
    const int b = blockIdx.x;
    const int tid = threadIdx.x;
    __shared__ float red[256];
    const float* pr = pred + (size_t)b * 4096;
    float sum = 0.f;
    #pragma unroll
    for (int i = 0; i < 8; i++) {
        const int s = tid + i * 256;
        const float l0 = pr[2 * s], l1 = pr[2 * s + 1];
        const float mm = fmaxf(l0, l1);
        const float z0 = expf(l0 - mm), z1 = expf(l1 - mm);
        const float Z = z0 + z1;
        const float lz = logf(Z);
        const float p0 = z0 / Z, p1 = z1 / Z;
        const float lp0 = (l0 - mm) - lz, lp1 = (l1 - mm) - lz;
        sum += -(p0 * lp0 + p1 * lp1) * 1.4426950408889634f; // 1/ln2
    }
    red[tid] = sum; __syncthreads();
    for (int off = 128; off > 0; off >>= 1) {
        if (tid < off) red[tid] += red[tid + off];
        __syncthreads();
    }
    #pragma unroll
    for (int i = 0; i < 16; i++) {
        const int jj = tid + i * 256;
        dout[(size_t)(b * 4096 + jj) * T_ + t] = pr[jj];
    }
    if (tid == 0) {
        const float ne = red[0] * (1.f / S_);
        const size_t base = (size_t)B_ * 4096 * T_;
        dout[base + (size_t)(b * 2 + 0) * T_ + t] = ne;
        dout[base + (size_t)(b * 2 + 1) * T_ + t] = 1.f - ne;
    }
}

// ---------------------------------------------------------------------------
extern "C" void kernel_launch(void* const* d_in, const int* in_sizes, int n_in,
                              void* d_out, int out_size, void* d_ws, size_t ws_size,
                              hipStream_t stream)
{
    const int*   tokens    = (const int*)  d_in[0];
    const float* emb       = (const float*)d_in[1];
    const float* W_pos     = (const float*)d_in[2];
    const float* b_pos     = (const float*)d_in[3];
    const float* Wq        = (const float*)d_in[4];
    const float* bq        = (const float*)d_in[5];
    const float* Wk        = (const float*)d_in[6];
    const float* bk        = (const float*)d_in[7];
    const float* Wv        = (const float*)d_in[8];
    const float* bv        = (const float*)d_in[9];
    const float* Wo        = (const float*)d_in[10];
    const float* bo        = (const float*)d_in[11];
    const float* Ws        = (const float*)d_in[12];
    const float* bs        = (const float*)d_in[13];
    const float* ln_s_g    = (const float*)d_in[14];
    const float* ln_s_b    = (const float*)d_in[15];
    const float* ln_n_g    = (const float*)d_in[16];
    const float* ln_n_b    = (const float*)d_in[17];
    const float* Wn        = (const float*)d_in[18];
    const float* bn        = (const float*)d_in[19];
    const float* temp      = (const float*)d_in[20];
    const float* Wout      = (const float*)d_in[21];
    const float* bout      = (const float*)d_in[22];
    const float* start_act = (const float*)d_in[23];
    const float* start_tr  = (const float*)d_in[24];
    const float* dec_act   = (const float*)d_in[25];
    const float* dec_out   = (const float*)d_in[26];
    float* out = (float*)d_out;
    float* w = (float*)d_ws;

    // workspace layout (floats)
    size_t off = 0;
    float* f2     = w + off; off += (size_t)2 * S_ * 512;      // 2,097,152
    float* Ktab   = w + off; off += (size_t)2 * S_ * 512;
    float* Vtab   = w + off; off += (size_t)2 * S_ * 512;
    float* act    = w + off; off += (size_t)B_ * D_MODEL_;
    float* cat    = w + off; off += (size_t)B_ * 2560;
    float* a_a    = w + off; off += (size_t)B_ * REP_;
    float* a_o    = w + off; off += (size_t)B_ * REP_;
    float* s_act  = w + off; off += (size_t)B_ * REP_;
    float* s_out  = w + off; off += (size_t)B_ * REP_;
    float* qbuf   = w + off; off += (size_t)B_ * 512;
    float* o_attn = w + off; off += (size_t)B_ * 512;
    float* pre    = w + off; off += (size_t)B_ * 4096;
    float* state  = w + off; off += (size_t)B_ * D_MODEL_;
    float* trace  = w + off; off += (size_t)B_ * D_MODEL_ * M_;
    float* predb  = w + off; off += (size_t)B_ * 4096;

    // ---- pre-loop ----
    feats_kernel<<<(2 * S_ * 512) / 256, 256, 0, stream>>>(emb, W_pos, b_pos, f2);
    init_act_kernel<<<(B_ * D_MODEL_) / 256, 256, 0, stream>>>(start_act, act, cat);
    init_trace_kernel<<<(B_ * D_MODEL_ * M_) / 256, 256, 0, stream>>>(start_tr, trace);
    // Ktab = f2 @ Wk + bk ; Vtab = f2 @ Wv + bv   (M=4096,N=512,K=512)
    gemm_f32<<<dim3(512 / BN, (2 * S_) / BM), 256, 0, stream>>>(
        f2, 512, Wk, bk, Ktab, 512, 2 * S_, 512, 512);
    gemm_f32<<<dim3(512 / BN, (2 * S_) / BM), 256, 0, stream>>>(
        f2, 512, Wv, bv, Vtab, 512, 2 * S_, 512, 512);

    // ---- T iterations ----
    for (int t = 0; t < T_; t++) {
        // sync action (last 64 of act)
        sync_kernel<<<dim3(B_, 9), 256, 0, stream>>>(act, a_a, dec_act, t, D_MODEL_ - NSY_, s_act);
        // q = s_act @ Wq + bq   (128,512,K=2080)
        gemm_f32<<<dim3(512 / BN, B_ / BM), 256, 0, stream>>>(
            s_act, REP_, Wq, bq, qbuf, 512, B_, 512, REP_);
        // attention
        attn_kernel<<<B_ * H_, 256, 0, stream>>>(qbuf, Ktab, Vtab, tokens, o_attn);
        // o_proj = o_attn @ Wo + bo -> cat[:, :512]
        gemm_f32<<<dim3(512 / BN, B_ / BM), 256, 0, stream>>>(
            o_attn, 512, Wo, bo, cat, 2560, B_, 512, 512);
        // pre = cat @ Ws + bs   (128,4096,K=2560)
        gemm_f32<<<dim3(4096 / BN, B_ / BM), 256, 0, stream>>>(
            cat, 2560, Ws, bs, pre, 4096, B_, 4096, 2560);
        // state = LN(glu(pre))
        glu_ln_kernel<<<B_, 256, 0, stream>>>(pre, ln_s_g, ln_s_b, state);
        // trace shift + LN + y -> act (also writes cat[:,512:])
        trace_kernel<<<(B_ * D_MODEL_) / 256, 256, 0, stream>>>(
            trace, state, ln_n_g, ln_n_b, Wn, bn, temp, act, cat);
        // sync out (first 64 of act)
        sync_kernel<<<dim3(B_, 9), 256, 0, stream>>>(act, a_o, dec_out, t, 0, s_out);
        // pred = s_out @ Wout + bout  (128,4096,K=2080)
        gemm_f32<<<dim3(4096 / BN, B_ / BM), 256, 0, stream>>>(
            s_out, REP_, Wout, bout, predb, 4096, B_, 4096, REP_);
        // write preds + certs
        out_kernel<<<B_, 256, 0, stream>>>(predb, out, t);
    }
}

// Round 2
// 3688.433 us; speedup vs baseline: 1.6218x; 1.6218x over previous
//
#include <hip/hip_runtime.h>
#include <hip/hip_bf16.h>
#include <math.h>

#define B_ 128
#define S_ 2048
#define D_IN_ 512
#define D_MODEL_ 2048
#define M_ 25
#define NSY_ 64
#define H_ 8
#define T_ 10
#define REP_ 2080
#define DH_ 64

// ---------------------------------------------------------------------------
// Tiled f32 GEMM with split-K: C[M,N] (+)= A[M,K] @ B[K,N]
// grid = (N/BN, M/BM, Z). If Z==1: C = acc + bias (direct store).
// If Z>1: C must be pre-initialized with bias; blocks atomicAdd partials.
// BM=128, BN=32, BK=32; 256 threads; 4x4 micro-tile.
// ---------------------------------------------------------------------------
#define BM 128
#define BN 32
#define BK 32

__global__ __launch_bounds__(256) void gemm_f32(
    const float* __restrict__ A, int lda,
    const float* __restrict__ Bm, // ldb == N
    const float* __restrict__ bias,
    float* __restrict__ C, int ldc,
    int M, int N, int K, int kchunk)
{
    const int nb = blockIdx.x, mb = blockIdx.y, zb = blockIdx.z;
    const int k0 = zb * kchunk;
    const int k1 = min(K, k0 + kchunk);
    __shared__ float As[BK][BM + 4];
    __shared__ float Bs[BK][BN + 4];
    const int tid = threadIdx.x;
    const int tm = tid >> 3;   // 0..31 -> 4 rows each
    const int tn = tid & 7;    // 0..7  -> 4 cols each
    float acc[4][4] = {};
    const float* Ablk = A + (size_t)mb * BM * lda;
    const float* Bblk = Bm + (size_t)nb * BN;

    const int r = tid >> 3;          // 0..31
    const int c4 = (tid & 7) * 4;    // 0..28

    for (int kk0 = k0; kk0 < k1; kk0 += BK) {
        // A tile: 128 x 32, float4 per thread x4 passes, store transposed
        #pragma unroll
        for (int i = 0; i < 4; i++) {
            const int m = r + 32 * i;
            float4 v = *(const float4*)(Ablk + (size_t)m * lda + kk0 + c4);
            As[c4 + 0][m] = v.x; As[c4 + 1][m] = v.y;
            As[c4 + 2][m] = v.z; As[c4 + 3][m] = v.w;
        }
        // B tile: 32 x 32, one float4 per thread
        {
            float4 v = *(const float4*)(Bblk + (size_t)(kk0 + r) * N + c4);
            *(float4*)&Bs[r][c4] = v;
        }
        __syncthreads();
        #pragma unroll
        for (int kk = 0; kk < BK; kk++) {
            float4 a = *(const float4*)&As[kk][tm * 4];
            float4 b = *(const float4*)&Bs[kk][tn * 4];
            float av[4] = {a.x, a.y, a.z, a.w};
            float bv[4] = {b.x, b.y, b.z, b.w};
            #pragma unroll
            for (int rr = 0; rr < 4; rr++)
                #pragma unroll
                for (int cc = 0; cc < 4; cc++)
                    acc[rr][cc] += av[rr] * bv[cc];
        }
        __syncthreads();
    }

    if (gridDim.z == 1) {
        #pragma unroll
        for (int rr = 0; rr < 4; rr++) {
            const int m = mb * BM + tm * 4 + rr;
            const int n = nb * BN + tn * 4;
            float4 o;
            o.x = acc[rr][0] + bias[n + 0];
            o.y = acc[rr][1] + bias[n + 1];
            o.z = acc[rr][2] + bias[n + 2];
            o.w = acc[rr][3] + bias[n + 3];
            *(float4*)&C[(size_t)m * ldc + n] = o;
        }
    } else {
        #pragma unroll
        for (int rr = 0; rr < 4; rr++) {
            const int m = mb * BM + tm * 4 + rr;
            const int n = nb * BN + tn * 4;
            #pragma unroll
            for (int cc = 0; cc < 4; cc++)
                atomicAdd(&C[(size_t)m * ldc + n + cc], acc[rr][cc]);
        }
    }
}

// ---------------------------------------------------------------------------
// C[m, n] = bias[n]  (for split-K targets), float4 wide
// ---------------------------------------------------------------------------
__global__ void init_bias_kernel(float* __restrict__ C, int ldc,
                                 const float* __restrict__ bias,
                                 int M, int N)
{
    const int gid = blockIdx.x * 256 + threadIdx.x; // over M*N/4
    const int n4 = N >> 2;
    if (gid >= M * n4) return;
    const int m = gid / n4, n = (gid - m * n4) * 4;
    *(float4*)&C[(size_t)m * ldc + n] = *(const float4*)&bias[n];
}

// ---------------------------------------------------------------------------
__global__ void feats_kernel(const float* __restrict__ emb,
                             const float* __restrict__ Wp,
                             const float* __restrict__ bp,
                             float* __restrict__ f2)
{
    const int gid = blockIdx.x * 256 + threadIdx.x; // 2*S*512
    const int k = gid & 511;
    const int s = (gid >> 9) & (S_ - 1);
    const int c = gid >> 20;
    const float th = 3.14159265358979323846f * (float)s / (float)(S_ - 1);
    f2[gid] = emb[c * 512 + k] + (-sinf(th)) * Wp[k] + cosf(th) * Wp[512 + k] + bp[k];
}

__global__ void init_act_kernel(const float* __restrict__ sa,
                                float* __restrict__ act,
                                float* __restrict__ cat)
{
    const int gid = blockIdx.x * 256 + threadIdx.x; // B*2048
    const int b = gid >> 11, n = gid & 2047;
    const float v = sa[n];
    act[gid] = v;
    cat[(size_t)b * 2560 + 512 + n] = v;
}

__global__ void init_trace_kernel(const float* __restrict__ st,
                                  float* __restrict__ trace)
{
    const int gid = blockIdx.x * 256 + threadIdx.x; // B*2048*25
    trace[gid] = st[gid % (D_MODEL_ * M_)];
}

// ---------------------------------------------------------------------------
__global__ void sync_kernel(const float* __restrict__ act,
                            float* __restrict__ alpha,
                            const float* __restrict__ decay,
                            const int t, const int off,
                            float* __restrict__ sout)
{
    const int b = blockIdx.x;
    const int p = blockIdx.y * 256 + threadIdx.x;
    if (p >= REP_) return;
    int i = 0, rem = p;
    while (rem >= NSY_ - i) { rem -= NSY_ - i; i++; }
    const int j = i + rem;
    const float si = act[(size_t)b * D_MODEL_ + off + i];
    const float sj = act[(size_t)b * D_MODEL_ + off + j];
    const float pair = si * sj;
    const float r = expf(-decay[p]);
    float a;
    if (t == 0) a = pair;
    else        a = r * alpha[(size_t)b * REP_ + p] + pair;
    alpha[(size_t)b * REP_ + p] = a;
    float bta = 1.f;
    for (int k = 0; k < t; k++) bta = r * bta + 1.f;
    sout[(size_t)b * REP_ + p] = a / sqrtf(bta);
}

// ---------------------------------------------------------------------------
__global__ __launch_bounds__(256) void attn_kernel(
    const float* __restrict__ q,      // (B,512)
    const float* __restrict__ Ktab,   // (2,S,512)
    const float* __restrict__ Vtab,   // (2,S,512)
    const int*   __restrict__ tokens, // (B,S)
    float* __restrict__ o)            // (B,512)
{
    const int bh = blockIdx.x;
    const int b = bh >> 3, h = bh & 7;
    __shared__ float qs[64];
    __shared__ float sc[S_];
    __shared__ float red[256];
    __shared__ float po[4][64];
    const int tid = threadIdx.x;
    if (tid < 64) qs[tid] = q[(size_t)b * 512 + h * 64 + tid];
    __syncthreads();

    const int* trow = tokens + (size_t)b * S_;
    float lmax = -1e30f;
    #pragma unroll
    for (int i = 0; i < 8; i++) {
        const int s = tid + i * 256;
        const int tok = trow[s];
        const float4* kv = (const float4*)(Ktab + ((size_t)(tok * S_ + s)) * 512 + h * 64);
        float acc = 0.f;
        #pragma unroll
        for (int d4 = 0; d4 < 16; d4++) {
            float4 k4 = kv[d4];
            acc += qs[d4*4+0]*k4.x + qs[d4*4+1]*k4.y + qs[d4*4+2]*k4.z + qs[d4*4+3]*k4.w;
        }
        acc *= 0.125f; // 1/sqrt(64)
        sc[s] = acc;
        lmax = fmaxf(lmax, acc);
    }
    red[tid] = lmax; __syncthreads();
    for (int off = 128; off > 0; off >>= 1) {
        if (tid < off) red[tid] = fmaxf(red[tid], red[tid + off]);
        __syncthreads();
    }
    const float mx = red[0];
    __syncthreads();

    float lsum = 0.f;
    #pragma unroll
    for (int i = 0; i < 8; i++) {
        const int s = tid + i * 256;
        const float e = expf(sc[s] - mx);
        sc[s] = e;
        lsum += e;
    }
    red[tid] = lsum; __syncthreads();
    for (int off = 128; off > 0; off >>= 1) {
        if (tid < off) red[tid] += red[tid + off];
        __syncthreads();
    }
    const float inv = 1.f / red[0];

    const int d = tid & 63, grp = tid >> 6;
    float acc = 0.f;
    const int s0 = grp * 512;
    for (int s = s0; s < s0 + 512; s++) {
        const int tok = trow[s];
        acc += sc[s] * Vtab[((size_t)(tok * S_ + s)) * 512 + h * 64 + d];
    }
    po[grp][d] = acc; __syncthreads();
    if (tid < 64) {
        o[(size_t)b * 512 + h * 64 + tid] =
            (po[0][tid] + po[1][tid] + po[2][tid] + po[3][tid]) * inv;
    }
}

// ---------------------------------------------------------------------------
__global__ __launch_bounds__(256) void glu_ln_kernel(
    const float* __restrict__ pre,   // (B,4096)
    const float* __restrict__ g,
    const float* __restrict__ bta,
    float* __restrict__ state)       // (B,2048)
{
    const int b = blockIdx.x;
    const int tid = threadIdx.x;
    __shared__ float v[D_MODEL_];
    __shared__ float r1[256], r2[256];
    float s1 = 0.f, s2 = 0.f;
    #pragma unroll
    for (int i = 0; i < 8; i++) {
        const int dd = tid + i * 256;
        const float g1 = pre[(size_t)b * 4096 + dd];
        const float g2 = pre[(size_t)b * 4096 + 2048 + dd];
        const float val = g1 * (1.f / (1.f + expf(-g2)));
        v[dd] = val; s1 += val; s2 += val * val;
    }
    r1[tid] = s1; r2[tid] = s2; __syncthreads();
    for (int off = 128; off > 0; off >>= 1) {
        if (tid < off) { r1[tid] += r1[tid + off]; r2[tid] += r2[tid + off]; }
        __syncthreads();
    }
    const float mu = r1[0] * (1.f / D_MODEL_);
    const float var = fmaxf(r2[0] * (1.f / D_MODEL_) - mu * mu, 0.f);
    const float inv = 1.f / sqrtf(var + 1e-5f);
    #pragma unroll
    for (int i = 0; i < 8; i++) {
        const int dd = tid + i * 256;
        state[(size_t)b * D_MODEL_ + dd] = (v[dd] - mu) * inv * g[dd] + bta[dd];
    }
}

// ---------------------------------------------------------------------------
__global__ void trace_kernel(float* __restrict__ trace,      // (B,2048,25)
                             const float* __restrict__ state,// (B,2048)
                             const float* __restrict__ ln_g, // (25)
                             const float* __restrict__ ln_b, // (25)
                             const float* __restrict__ Wn,   // (25,2,2048)
                             const float* __restrict__ bn,   // (2048,2)
                             const float* __restrict__ temp, // (1)
                             float* __restrict__ act,        // (B,2048)
                             float* __restrict__ cat)        // (B,2560)
{
    const int gid = blockIdx.x * 256 + threadIdx.x; // B*2048
    const int b = gid >> 11, n = gid & 2047;
    float* tr = trace + (size_t)gid * M_;
    float x[M_];
    #pragma unroll
    for (int m = 0; m < M_ - 1; m++) x[m] = tr[m + 1];
    x[M_ - 1] = state[gid];
    #pragma unroll
    for (int m = 0; m < M_; m++) tr[m] = x[m];
    float s1 = 0.f, s2 = 0.f;
    #pragma unroll
    for (int m = 0; m < M_; m++) { s1 += x[m]; s2 += x[m] * x[m]; }
    const float mu = s1 * (1.f / M_);
    const float var = fmaxf(s2 * (1.f / M_) - mu * mu, 0.f);
    const float inv = 1.f / sqrtf(var + 1e-5f);
    float y0 = bn[n * 2 + 0], y1 = bn[n * 2 + 1];
    #pragma unroll
    for (int m = 0; m < M_; m++) {
        const float xn = (x[m] - mu) * inv * ln_g[m] + ln_b[m];
        y0 += xn * Wn[(size_t)(m * 2 + 0) * D_MODEL_ + n];
        y1 += xn * Wn[(size_t)(m * 2 + 1) * D_MODEL_ + n];
    }
    const float a = y0 * (1.f / (1.f + expf(-y1))) / temp[0];
    act[gid] = a;
    cat[(size_t)b * 2560 + 512 + n] = a;
}

// ---------------------------------------------------------------------------
__global__ __launch_bounds__(256) void out_kernel(
    const float* __restrict__ pred,  // (B,4096)
    float* __restrict__ dout,
    const int t)
{
    const int b = blockIdx.x;
    const int tid = threadIdx.x;
    __shared__ float red[256];
    const float* pr = pred + (size_t)b * 4096;
    float sum = 0.f;
    #pragma unroll
    for (int i = 0; i < 8; i++) {
        const int s = tid + i * 256;
        const float l0 = pr[2 * s], l1 = pr[2 * s + 1];
        const float mm = fmaxf(l0, l1);
        const float z0 = expf(l0 - mm), z1 = expf(l1 - mm);
        const float Z = z0 + z1;
        const float lz = logf(Z);
        const float p0 = z0 / Z, p1 = z1 / Z;
        const float lp0 = (l0 - mm) - lz, lp1 = (l1 - mm) - lz;
        sum += -(p0 * lp0 + p1 * lp1) * 1.4426950408889634f; // 1/ln2
    }
    red[tid] = sum; __syncthreads();
    for (int off = 128; off > 0; off >>= 1) {
        if (tid < off) red[tid] += red[tid + off];
        __syncthreads();
    }
    #pragma unroll
    for (int i = 0; i < 16; i++) {
        const int jj = tid + i * 256;
        dout[(size_t)(b * 4096 + jj) * T_ + t] = pr[jj];
    }
    if (tid == 0) {
        const float ne = red[0] * (1.f / S_);
        const size_t base = (size_t)B_ * 4096 * T_;
        dout[base + (size_t)(b * 2 + 0) * T_ + t] = ne;
        dout[base + (size_t)(b * 2 + 1) * T_ + t] = 1.f - ne;
    }
}

// ---------------------------------------------------------------------------
extern "C" void kernel_launch(void* const* d_in, const int* in_sizes, int n_in,
                              void* d_out, int out_size, void* d_ws, size_t ws_size,
                              hipStream_t stream)
{
    const int*   tokens    = (const int*)  d_in[0];
    const float* emb       = (const float*)d_in[1];
    const float* W_pos     = (const float*)d_in[2];
    const float* b_pos     = (const float*)d_in[3];
    const float* Wq        = (const float*)d_in[4];
    const float* bq        = (const float*)d_in[5];
    const float* Wk        = (const float*)d_in[6];
    const float* bk        = (const float*)d_in[7];
    const float* Wv        = (const float*)d_in[8];
    const float* bv        = (const float*)d_in[9];
    const float* Wo        = (const float*)d_in[10];
    const float* bo        = (const float*)d_in[11];
    const float* Ws        = (const float*)d_in[12];
    const float* bs        = (const float*)d_in[13];
    const float* ln_s_g    = (const float*)d_in[14];
    const float* ln_s_b    = (const float*)d_in[15];
    const float* ln_n_g    = (const float*)d_in[16];
    const float* ln_n_b    = (const float*)d_in[17];
    const float* Wn        = (const float*)d_in[18];
    const float* bn        = (const float*)d_in[19];
    const float* temp      = (const float*)d_in[20];
    const float* Wout      = (const float*)d_in[21];
    const float* bout      = (const float*)d_in[22];
    const float* start_act = (const float*)d_in[23];
    const float* start_tr  = (const float*)d_in[24];
    const float* dec_act   = (const float*)d_in[25];
    const float* dec_out   = (const float*)d_in[26];
    float* out = (float*)d_out;
    float* w = (float*)d_ws;

    // workspace layout (floats)
    size_t off = 0;
    float* f2     = w + off; off += (size_t)2 * S_ * 512;
    float* Ktab   = w + off; off += (size_t)2 * S_ * 512;
    float* Vtab   = w + off; off += (size_t)2 * S_ * 512;
    float* act    = w + off; off += (size_t)B_ * D_MODEL_;
    float* cat    = w + off; off += (size_t)B_ * 2560;
    float* a_a    = w + off; off += (size_t)B_ * REP_;
    float* a_o    = w + off; off += (size_t)B_ * REP_;
    float* s_act  = w + off; off += (size_t)B_ * REP_;
    float* s_out  = w + off; off += (size_t)B_ * REP_;
    float* qbuf   = w + off; off += (size_t)B_ * 512;
    float* o_attn = w + off; off += (size_t)B_ * 512;
    float* pre    = w + off; off += (size_t)B_ * 4096;
    float* state  = w + off; off += (size_t)B_ * D_MODEL_;
    float* trace  = w + off; off += (size_t)B_ * D_MODEL_ * M_;
    float* predb  = w + off; off += (size_t)B_ * 4096;

    // ---- pre-loop ----
    feats_kernel<<<(2 * S_ * 512) / 256, 256, 0, stream>>>(emb, W_pos, b_pos, f2);
    init_act_kernel<<<(B_ * D_MODEL_) / 256, 256, 0, stream>>>(start_act, act, cat);
    init_trace_kernel<<<(B_ * D_MODEL_ * M_) / 256, 256, 0, stream>>>(start_tr, trace);
    // Ktab/Vtab: M=4096,N=512,K=512, no split (512 blocks, direct store+bias)
    gemm_f32<<<dim3(512 / BN, (2 * S_) / BM, 1), 256, 0, stream>>>(
        f2, 512, Wk, bk, Ktab, 512, 2 * S_, 512, 512, 512);
    gemm_f32<<<dim3(512 / BN, (2 * S_) / BM, 1), 256, 0, stream>>>(
        f2, 512, Wv, bv, Vtab, 512, 2 * S_, 512, 512, 512);

    // ---- T iterations ----
    for (int t = 0; t < T_; t++) {
        // sync action (last 64 of act)
        sync_kernel<<<dim3(B_, 9), 256, 0, stream>>>(act, a_a, dec_act, t, D_MODEL_ - NSY_, s_act);

        // q = s_act @ Wq + bq : M=128,N=512,K=2080 ; 13 z-chunks of 160 -> 208 blocks
        init_bias_kernel<<<(B_ * 512 / 4 + 255) / 256, 256, 0, stream>>>(qbuf, 512, bq, B_, 512);
        gemm_f32<<<dim3(512 / BN, 1, 13), 256, 0, stream>>>(
            s_act, REP_, Wq, bq, qbuf, 512, B_, 512, REP_, 160);

        // attention
        attn_kernel<<<B_ * H_, 256, 0, stream>>>(qbuf, Ktab, Vtab, tokens, o_attn);

        // o_proj -> cat[:, :512] : M=128,N=512,K=512 ; 8 z-chunks of 64 -> 128 blocks
        init_bias_kernel<<<(B_ * 512 / 4 + 255) / 256, 256, 0, stream>>>(cat, 2560, bo, B_, 512);
        gemm_f32<<<dim3(512 / BN, 1, 8), 256, 0, stream>>>(
            o_attn, 512, Wo, bo, cat, 2560, B_, 512, 512, 64);

        // pre = cat @ Ws + bs : M=128,N=4096,K=2560 ; 8 z-chunks of 320 -> 1024 blocks
        init_bias_kernel<<<(B_ * 4096 / 4 + 255) / 256, 256, 0, stream>>>(pre, 4096, bs, B_, 4096);
        gemm_f32<<<dim3(4096 / BN, 1, 8), 256, 0, stream>>>(
            cat, 2560, Ws, bs, pre, 4096, B_, 4096, 2560, 320);

        // state = LN(glu(pre))
        glu_ln_kernel<<<B_, 256, 0, stream>>>(pre, ln_s_g, ln_s_b, state);
        // trace shift + LN + y -> act (also writes cat[:,512:])
        trace_kernel<<<(B_ * D_MODEL_) / 256, 256, 0, stream>>>(
            trace, state, ln_n_g, ln_n_b, Wn, bn, temp, act, cat);

        // sync out (first 64 of act)
        sync_kernel<<<dim3(B_, 9), 256, 0, stream>>>(act, a_o, dec_out, t, 0, s_out);

        // pred = s_out @ Wout + bout : M=128,N=4096,K=2080 ; 7 z-chunks of 320 -> 896 blocks
        init_bias_kernel<<<(B_ * 4096 / 4 + 255) / 256, 256, 0, stream>>>(predb, 4096, bout, B_, 4096);
        gemm_f32<<<dim3(4096 / BN, 1, 7), 256, 0, stream>>>(
            s_out, REP_, Wout, bout, predb, 4096, B_, 4096, REP_, 320);

        // write preds + certs
        out_kernel<<<B_, 256, 0, stream>>>(predb, out, t);
    }
}

// Round 3
// 3042.569 us; speedup vs baseline: 1.9661x; 1.2123x over previous
//
#include <hip/hip_runtime.h>
#include <hip/hip_bf16.h>
#include <math.h>

#define B_ 128
#define S_ 2048
#define D_IN_ 512
#define D_MODEL_ 2048
#define M_ 25
#define NSY_ 64
#define H_ 8
#define T_ 10
#define REP_ 2080
#define DH_ 64

// ---------------------------------------------------------------------------
// Tiled f32 GEMM with split-K: C[M,N] (+)= A[M,K] @ B[K,N]
// grid = (N/BN, M/BM, Z). If Z==1: C = acc + bias (direct store).
// If Z>1: C must be pre-initialized with bias; blocks atomicAdd partials.
// BM=128, BN=32, BK=32; 256 threads; 4x4 micro-tile.
// ---------------------------------------------------------------------------
#define BM 128
#define BN 32
#define BK 32

__global__ __launch_bounds__(256) void gemm_f32(
    const float* __restrict__ A, int lda,
    const float* __restrict__ Bm, // ldb == N
    const float* __restrict__ bias,
    float* __restrict__ C, int ldc,
    int M, int N, int K, int kchunk)
{
    const int nb = blockIdx.x, mb = blockIdx.y, zb = blockIdx.z;
    const int k0 = zb * kchunk;
    const int k1 = min(K, k0 + kchunk);
    __shared__ float As[BK][BM + 4];
    __shared__ float Bs[BK][BN + 4];
    const int tid = threadIdx.x;
    const int tm = tid >> 3;   // 0..31 -> 4 rows each
    const int tn = tid & 7;    // 0..7  -> 4 cols each
    float acc[4][4] = {};
    const float* Ablk = A + (size_t)mb * BM * lda;
    const float* Bblk = Bm + (size_t)nb * BN;

    const int r = tid >> 3;          // 0..31
    const int c4 = (tid & 7) * 4;    // 0..28

    for (int kk0 = k0; kk0 < k1; kk0 += BK) {
        #pragma unroll
        for (int i = 0; i < 4; i++) {
            const int m = r + 32 * i;
            float4 v = *(const float4*)(Ablk + (size_t)m * lda + kk0 + c4);
            As[c4 + 0][m] = v.x; As[c4 + 1][m] = v.y;
            As[c4 + 2][m] = v.z; As[c4 + 3][m] = v.w;
        }
        {
            float4 v = *(const float4*)(Bblk + (size_t)(kk0 + r) * N + c4);
            *(float4*)&Bs[r][c4] = v;
        }
        __syncthreads();
        #pragma unroll
        for (int kk = 0; kk < BK; kk++) {
            float4 a = *(const float4*)&As[kk][tm * 4];
            float4 b = *(const float4*)&Bs[kk][tn * 4];
            float av[4] = {a.x, a.y, a.z, a.w};
            float bv[4] = {b.x, b.y, b.z, b.w};
            #pragma unroll
            for (int rr = 0; rr < 4; rr++)
                #pragma unroll
                for (int cc = 0; cc < 4; cc++)
                    acc[rr][cc] += av[rr] * bv[cc];
        }
        __syncthreads();
    }

    if (gridDim.z == 1) {
        #pragma unroll
        for (int rr = 0; rr < 4; rr++) {
            const int m = mb * BM + tm * 4 + rr;
            const int n = nb * BN + tn * 4;
            float4 o;
            o.x = acc[rr][0] + bias[n + 0];
            o.y = acc[rr][1] + bias[n + 1];
            o.z = acc[rr][2] + bias[n + 2];
            o.w = acc[rr][3] + bias[n + 3];
            *(float4*)&C[(size_t)m * ldc + n] = o;
        }
    } else {
        #pragma unroll
        for (int rr = 0; rr < 4; rr++) {
            const int m = mb * BM + tm * 4 + rr;
            const int n = nb * BN + tn * 4;
            #pragma unroll
            for (int cc = 0; cc < 4; cc++)
                atomicAdd(&C[(size_t)m * ldc + n + cc], acc[rr][cc]);
        }
    }
}

// ---------------------------------------------------------------------------
__global__ void init_bias_kernel(float* __restrict__ C, int ldc,
                                 const float* __restrict__ bias,
                                 int M, int N)
{
    const int gid = blockIdx.x * 256 + threadIdx.x; // over M*N/4
    const int n4 = N >> 2;
    if (gid >= M * n4) return;
    const int m = gid / n4, n = (gid - m * n4) * 4;
    *(float4*)&C[(size_t)m * ldc + n] = *(const float4*)&bias[n];
}

// ---------------------------------------------------------------------------
// f32 -> bf16 cast (4 elements/thread)
// ---------------------------------------------------------------------------
__global__ void cast_bf16_kernel(const float* __restrict__ src,
                                 __hip_bfloat16* __restrict__ dst, int n)
{
    const int gid = (blockIdx.x * 256 + threadIdx.x) * 4;
    if (gid >= n) return;
    float4 v = *(const float4*)(src + gid);
    dst[gid + 0] = __float2bfloat16(v.x);
    dst[gid + 1] = __float2bfloat16(v.y);
    dst[gid + 2] = __float2bfloat16(v.z);
    dst[gid + 3] = __float2bfloat16(v.w);
}

// ---------------------------------------------------------------------------
__global__ void feats_kernel(const float* __restrict__ emb,
                             const float* __restrict__ Wp,
                             const float* __restrict__ bp,
                             float* __restrict__ f2)
{
    const int gid = blockIdx.x * 256 + threadIdx.x; // 2*S*512
    const int k = gid & 511;
    const int s = (gid >> 9) & (S_ - 1);
    const int c = gid >> 20;
    const float th = 3.14159265358979323846f * (float)s / (float)(S_ - 1);
    f2[gid] = emb[c * 512 + k] + (-sinf(th)) * Wp[k] + cosf(th) * Wp[512 + k] + bp[k];
}

__global__ void init_act_kernel(const float* __restrict__ sa,
                                float* __restrict__ act,
                                float* __restrict__ cat)
{
    const int gid = blockIdx.x * 256 + threadIdx.x; // B*2048
    const int b = gid >> 11, n = gid & 2047;
    const float v = sa[n];
    act[gid] = v;
    cat[(size_t)b * 2560 + 512 + n] = v;
}

__global__ void init_trace_kernel(const float* __restrict__ st,
                                  float* __restrict__ trace)
{
    const int gid = blockIdx.x * 256 + threadIdx.x; // B*2048*25
    trace[gid] = st[gid % (D_MODEL_ * M_)];
}

// ---------------------------------------------------------------------------
__global__ void sync_kernel(const float* __restrict__ act,
                            float* __restrict__ alpha,
                            const float* __restrict__ decay,
                            const int t, const int off,
                            float* __restrict__ sout)
{
    const int b = blockIdx.x;
    const int p = blockIdx.y * 256 + threadIdx.x;
    if (p >= REP_) return;
    int i = 0, rem = p;
    while (rem >= NSY_ - i) { rem -= NSY_ - i; i++; }
    const int j = i + rem;
    const float si = act[(size_t)b * D_MODEL_ + off + i];
    const float sj = act[(size_t)b * D_MODEL_ + off + j];
    const float pair = si * sj;
    const float r = expf(-decay[p]);
    float a;
    if (t == 0) a = pair;
    else        a = r * alpha[(size_t)b * REP_ + p] + pair;
    alpha[(size_t)b * REP_ + p] = a;
    float bta = 1.f;
    for (int k = 0; k < t; k++) bta = r * bta + 1.f;
    sout[(size_t)b * REP_ + p] = a / sqrtf(bta);
}

// ---------------------------------------------------------------------------
// attention per (b,h) with bf16 K/V tables
// ---------------------------------------------------------------------------
__device__ __forceinline__ float bflo(unsigned u) { return __uint_as_float(u << 16); }
__device__ __forceinline__ float bfhi(unsigned u) { return __uint_as_float(u & 0xffff0000u); }

__global__ __launch_bounds__(256) void attn_kernel(
    const float* __restrict__ q,              // (B,512)
    const __hip_bfloat16* __restrict__ Kb,    // (2,S,512) bf16
    const __hip_bfloat16* __restrict__ Vb,    // (2,S,512) bf16
    const int*   __restrict__ tokens,         // (B,S)
    float* __restrict__ o)                    // (B,512)
{
    const int bh = blockIdx.x;
    const int b = bh >> 3, h = bh & 7;
    __shared__ float qs[64];
    __shared__ float sc[S_];
    __shared__ float red[256];
    __shared__ float po[32][68];   // +4 pad: store conflicts <=2-way
    const int tid = threadIdx.x;
    if (tid < 64) qs[tid] = q[(size_t)b * 512 + h * 64 + tid];
    __syncthreads();

    const int* trow = tokens + (size_t)b * S_;

    // ---- QK pass: 8 s per thread, 8x16B bf16 loads per s ----
    float lmax = -1e30f;
    #pragma unroll
    for (int i = 0; i < 8; i++) {
        const int s = tid + i * 256;
        const int tok = trow[s];
        const uint4* kp = (const uint4*)(Kb + ((size_t)(tok * S_ + s)) * 512 + h * 64);
        float acc = 0.f;
        #pragma unroll
        for (int j = 0; j < 8; j++) {
            uint4 r = kp[j];
            acc += qs[j*8+0]*bflo(r.x) + qs[j*8+1]*bfhi(r.x)
                 + qs[j*8+2]*bflo(r.y) + qs[j*8+3]*bfhi(r.y)
                 + qs[j*8+4]*bflo(r.z) + qs[j*8+5]*bfhi(r.z)
                 + qs[j*8+6]*bflo(r.w) + qs[j*8+7]*bfhi(r.w);
        }
        acc *= 0.125f; // 1/sqrt(64)
        sc[s] = acc;
        lmax = fmaxf(lmax, acc);
    }
    red[tid] = lmax; __syncthreads();
    for (int off = 128; off > 0; off >>= 1) {
        if (tid < off) red[tid] = fmaxf(red[tid], red[tid + off]);
        __syncthreads();
    }
    const float mx = red[0];
    __syncthreads();

    // ---- softmax numerator ----
    float lsum = 0.f;
    #pragma unroll
    for (int i = 0; i < 8; i++) {
        const int s = tid + i * 256;
        const float e = expf(sc[s] - mx);
        sc[s] = e;
        lsum += e;
    }
    red[tid] = lsum; __syncthreads();
    for (int off = 128; off > 0; off >>= 1) {
        if (tid < off) red[tid] += red[tid + off];
        __syncthreads();
    }
    const float inv = 1.f / red[0];
    __syncthreads();

    // ---- V pass: 32 s-groups x 8 dims/thread, 16B loads, 64 iters ----
    const int d8 = (tid & 7) * 8;
    const int g  = tid >> 3;          // 0..31
    float va[8] = {};
    #pragma unroll 4
    for (int it = 0; it < 64; it++) {
        const int s = g * 64 + ((it + g) & 63);   // stagger: distinct LDS banks
        const int tok = trow[s];
        const float p = sc[s];
        uint4 r = *(const uint4*)(Vb + ((size_t)(tok * S_ + s)) * 512 + h * 64 + d8);
        va[0] += p * bflo(r.x); va[1] += p * bfhi(r.x);
        va[2] += p * bflo(r.y); va[3] += p * bfhi(r.y);
        va[4] += p * bflo(r.z); va[5] += p * bfhi(r.z);
        va[6] += p * bflo(r.w); va[7] += p * bfhi(r.w);
    }
    *(float4*)&po[g][d8]     = make_float4(va[0], va[1], va[2], va[3]);
    *(float4*)&po[g][d8 + 4] = make_float4(va[4], va[5], va[6], va[7]);
    __syncthreads();
    if (tid < 64) {
        float acc = 0.f;
        #pragma unroll
        for (int gg = 0; gg < 32; gg++) acc += po[gg][tid];
        o[(size_t)b * 512 + h * 64 + tid] = acc * inv;
    }
}

// ---------------------------------------------------------------------------
__global__ __launch_bounds__(256) void glu_ln_kernel(
    const float* __restrict__ pre,   // (B,4096)
    const float* __restrict__ g,
    const float* __restrict__ bta,
    float* __restrict__ state)       // (B,2048)
{
    const int b = blockIdx.x;
    const int tid = threadIdx.x;
    __shared__ float v[D_MODEL_];
    __shared__ float r1[256], r2[256];
    float s1 = 0.f, s2 = 0.f;
    #pragma unroll
    for (int i = 0; i < 8; i++) {
        const int dd = tid + i * 256;
        const float g1 = pre[(size_t)b * 4096 + dd];
        const float g2 = pre[(size_t)b * 4096 + 2048 + dd];
        const float val = g1 * (1.f / (1.f + expf(-g2)));
        v[dd] = val; s1 += val; s2 += val * val;
    }
    r1[tid] = s1; r2[tid] = s2; __syncthreads();
    for (int off = 128; off > 0; off >>= 1) {
        if (tid < off) { r1[tid] += r1[tid + off]; r2[tid] += r2[tid + off]; }
        __syncthreads();
    }
    const float mu = r1[0] * (1.f / D_MODEL_);
    const float var = fmaxf(r2[0] * (1.f / D_MODEL_) - mu * mu, 0.f);
    const float inv = 1.f / sqrtf(var + 1e-5f);
    #pragma unroll
    for (int i = 0; i < 8; i++) {
        const int dd = tid + i * 256;
        state[(size_t)b * D_MODEL_ + dd] = (v[dd] - mu) * inv * g[dd] + bta[dd];
    }
}

// ---------------------------------------------------------------------------
__global__ void trace_kernel(float* __restrict__ trace,      // (B,2048,25)
                             const float* __restrict__ state,// (B,2048)
                             const float* __restrict__ ln_g, // (25)
                             const float* __restrict__ ln_b, // (25)
                             const float* __restrict__ Wn,   // (25,2,2048)
                             const float* __restrict__ bn,   // (2048,2)
                             const float* __restrict__ temp, // (1)
                             float* __restrict__ act,        // (B,2048)
                             float* __restrict__ cat)        // (B,2560)
{
    const int gid = blockIdx.x * 256 + threadIdx.x; // B*2048
    const int b = gid >> 11, n = gid & 2047;
    float* tr = trace + (size_t)gid * M_;
    float x[M_];
    #pragma unroll
    for (int m = 0; m < M_ - 1; m++) x[m] = tr[m + 1];
    x[M_ - 1] = state[gid];
    #pragma unroll
    for (int m = 0; m < M_; m++) tr[m] = x[m];
    float s1 = 0.f, s2 = 0.f;
    #pragma unroll
    for (int m = 0; m < M_; m++) { s1 += x[m]; s2 += x[m] * x[m]; }
    const float mu = s1 * (1.f / M_);
    const float var = fmaxf(s2 * (1.f / M_) - mu * mu, 0.f);
    const float inv = 1.f / sqrtf(var + 1e-5f);
    float y0 = bn[n * 2 + 0], y1 = bn[n * 2 + 1];
    #pragma unroll
    for (int m = 0; m < M_; m++) {
        const float xn = (x[m] - mu) * inv * ln_g[m] + ln_b[m];
        y0 += xn * Wn[(size_t)(m * 2 + 0) * D_MODEL_ + n];
        y1 += xn * Wn[(size_t)(m * 2 + 1) * D_MODEL_ + n];
    }
    const float a = y0 * (1.f / (1.f + expf(-y1))) / temp[0];
    act[gid] = a;
    cat[(size_t)b * 2560 + 512 + n] = a;
}

// ---------------------------------------------------------------------------
__global__ __launch_bounds__(256) void out_kernel(
    const float* __restrict__ pred,  // (B,4096)
    float* __restrict__ dout,
    const int t)
{
    const int b = blockIdx.x;
    const int tid = threadIdx.x;
    __shared__ float red[256];
    const float* pr = pred + (size_t)b * 4096;
    float sum = 0.f;
    #pragma unroll
    for (int i = 0; i < 8; i++) {
        const int s = tid + i * 256;
        const float l0 = pr[2 * s], l1 = pr[2 * s + 1];
        const float mm = fmaxf(l0, l1);
        const float z0 = expf(l0 - mm), z1 = expf(l1 - mm);
        const float Z = z0 + z1;
        const float lz = logf(Z);
        const float p0 = z0 / Z, p1 = z1 / Z;
        const float lp0 = (l0 - mm) - lz, lp1 = (l1 - mm) - lz;
        sum += -(p0 * lp0 + p1 * lp1) * 1.4426950408889634f; // 1/ln2
    }
    red[tid] = sum; __syncthreads();
    for (int off = 128; off > 0; off >>= 1) {
        if (tid < off) red[tid] += red[tid + off];
        __syncthreads();
    }
    #pragma unroll
    for (int i = 0; i < 16; i++) {
        const int jj = tid + i * 256;
        dout[(size_t)(b * 4096 + jj) * T_ + t] = pr[jj];
    }
    if (tid == 0) {
        const float ne = red[0] * (1.f / S_);
        const size_t base = (size_t)B_ * 4096 * T_;
        dout[base + (size_t)(b * 2 + 0) * T_ + t] = ne;
        dout[base + (size_t)(b * 2 + 1) * T_ + t] = 1.f - ne;
    }
}

// ---------------------------------------------------------------------------
extern "C" void kernel_launch(void* const* d_in, const int* in_sizes, int n_in,
                              void* d_out, int out_size, void* d_ws, size_t ws_size,
                              hipStream_t stream)
{
    const int*   tokens    = (const int*)  d_in[0];
    const float* emb       = (const float*)d_in[1];
    const float* W_pos     = (const float*)d_in[2];
    const float* b_pos     = (const float*)d_in[3];
    const float* Wq        = (const float*)d_in[4];
    const float* bq        = (const float*)d_in[5];
    const float* Wk        = (const float*)d_in[6];
    const float* bk        = (const float*)d_in[7];
    const float* Wv        = (const float*)d_in[8];
    const float* bv        = (const float*)d_in[9];
    const float* Wo        = (const float*)d_in[10];
    const float* bo        = (const float*)d_in[11];
    const float* Ws        = (const float*)d_in[12];
    const float* bs        = (const float*)d_in[13];
    const float* ln_s_g    = (const float*)d_in[14];
    const float* ln_s_b    = (const float*)d_in[15];
    const float* ln_n_g    = (const float*)d_in[16];
    const float* ln_n_b    = (const float*)d_in[17];
    const float* Wn        = (const float*)d_in[18];
    const float* bn        = (const float*)d_in[19];
    const float* temp      = (const float*)d_in[20];
    const float* Wout      = (const float*)d_in[21];
    const float* bout      = (const float*)d_in[22];
    const float* start_act = (const float*)d_in[23];
    const float* start_tr  = (const float*)d_in[24];
    const float* dec_act   = (const float*)d_in[25];
    const float* dec_out   = (const float*)d_in[26];
    float* out = (float*)d_out;
    float* w = (float*)d_ws;

    // workspace layout (floats)
    size_t off = 0;
    float* f2     = w + off; off += (size_t)2 * S_ * 512;
    float* Ktab   = w + off; off += (size_t)2 * S_ * 512;
    float* Vtab   = w + off; off += (size_t)2 * S_ * 512;
    float* act    = w + off; off += (size_t)B_ * D_MODEL_;
    float* cat    = w + off; off += (size_t)B_ * 2560;
    float* a_a    = w + off; off += (size_t)B_ * REP_;
    float* a_o    = w + off; off += (size_t)B_ * REP_;
    float* s_act  = w + off; off += (size_t)B_ * REP_;
    float* s_out  = w + off; off += (size_t)B_ * REP_;
    float* qbuf   = w + off; off += (size_t)B_ * 512;
    float* o_attn = w + off; off += (size_t)B_ * 512;
    float* pre    = w + off; off += (size_t)B_ * 4096;
    float* state  = w + off; off += (size_t)B_ * D_MODEL_;
    float* trace  = w + off; off += (size_t)B_ * D_MODEL_ * M_;
    float* predb  = w + off; off += (size_t)B_ * 4096;
    __hip_bfloat16* Kb = (__hip_bfloat16*)(w + off); off += (size_t)S_ * 512;  // 2*S*512 bf16 = S*512 floats
    __hip_bfloat16* Vb = (__hip_bfloat16*)(w + off); off += (size_t)S_ * 512;

    // ---- pre-loop ----
    feats_kernel<<<(2 * S_ * 512) / 256, 256, 0, stream>>>(emb, W_pos, b_pos, f2);
    init_act_kernel<<<(B_ * D_MODEL_) / 256, 256, 0, stream>>>(start_act, act, cat);
    init_trace_kernel<<<(B_ * D_MODEL_ * M_) / 256, 256, 0, stream>>>(start_tr, trace);
    // Ktab/Vtab: M=4096,N=512,K=512, no split (512 blocks, direct store+bias)
    gemm_f32<<<dim3(512 / BN, (2 * S_) / BM, 1), 256, 0, stream>>>(
        f2, 512, Wk, bk, Ktab, 512, 2 * S_, 512, 512, 512);
    gemm_f32<<<dim3(512 / BN, (2 * S_) / BM, 1), 256, 0, stream>>>(
        f2, 512, Wv, bv, Vtab, 512, 2 * S_, 512, 512, 512);
    // cast to bf16 tables
    cast_bf16_kernel<<<(2 * S_ * 512 / 4) / 256, 256, 0, stream>>>(Ktab, Kb, 2 * S_ * 512);
    cast_bf16_kernel<<<(2 * S_ * 512 / 4) / 256, 256, 0, stream>>>(Vtab, Vb, 2 * S_ * 512);

    // ---- T iterations ----
    for (int t = 0; t < T_; t++) {
        sync_kernel<<<dim3(B_, 9), 256, 0, stream>>>(act, a_a, dec_act, t, D_MODEL_ - NSY_, s_act);

        // q = s_act @ Wq + bq : 13 z-chunks of 160 -> 208 blocks
        init_bias_kernel<<<(B_ * 512 / 4 + 255) / 256, 256, 0, stream>>>(qbuf, 512, bq, B_, 512);
        gemm_f32<<<dim3(512 / BN, 1, 13), 256, 0, stream>>>(
            s_act, REP_, Wq, bq, qbuf, 512, B_, 512, REP_, 160);

        // attention (bf16 tables)
        attn_kernel<<<B_ * H_, 256, 0, stream>>>(qbuf, Kb, Vb, tokens, o_attn);

        // o_proj -> cat[:, :512] : 8 z-chunks of 64 -> 128 blocks
        init_bias_kernel<<<(B_ * 512 / 4 + 255) / 256, 256, 0, stream>>>(cat, 2560, bo, B_, 512);
        gemm_f32<<<dim3(512 / BN, 1, 8), 256, 0, stream>>>(
            o_attn, 512, Wo, bo, cat, 2560, B_, 512, 512, 64);

        // pre = cat @ Ws + bs : 8 z-chunks of 320 -> 1024 blocks
        init_bias_kernel<<<(B_ * 4096 / 4 + 255) / 256, 256, 0, stream>>>(pre, 4096, bs, B_, 4096);
        gemm_f32<<<dim3(4096 / BN, 1, 8), 256, 0, stream>>>(
            cat, 2560, Ws, bs, pre, 4096, B_, 4096, 2560, 320);

        glu_ln_kernel<<<B_, 256, 0, stream>>>(pre, ln_s_g, ln_s_b, state);
        trace_kernel<<<(B_ * D_MODEL_) / 256, 256, 0, stream>>>(
            trace, state, ln_n_g, ln_n_b, Wn, bn, temp, act, cat);

        sync_kernel<<<dim3(B_, 9), 256, 0, stream>>>(act, a_o, dec_out, t, 0, s_out);

        // pred = s_out @ Wout + bout : 7 z-chunks of 320 -> 896 blocks
        init_bias_kernel<<<(B_ * 4096 / 4 + 255) / 256, 256, 0, stream>>>(predb, 4096, bout, B_, 4096);
        gemm_f32<<<dim3(4096 / BN, 1, 7), 256, 0, stream>>>(
            s_out, REP_, Wout, bout, predb, 4096, B_, 4096, REP_, 320);

        out_kernel<<<B_, 256, 0, stream>>>(predb, out, t);
    }
}

// Round 4
// 1798.432 us; speedup vs baseline: 3.3262x; 1.6918x over previous
//
#include <hip/hip_runtime.h>
#include <hip/hip_bf16.h>
#include <math.h>

#define B_ 128
#define S_ 2048
#define D_IN_ 512
#define D_MODEL_ 2048
#define M_ 25
#define NSY_ 64
#define H_ 8
#define T_ 10
#define REP_ 2080
#define DH_ 64

typedef unsigned short ushort_t;
typedef __bf16 bf16x8 __attribute__((ext_vector_type(8)));
typedef float f32x4 __attribute__((ext_vector_type(4)));
typedef unsigned short us8 __attribute__((ext_vector_type(8)));

__device__ __forceinline__ ushort_t f2bf(float f) {
    __hip_bfloat16 h = __float2bfloat16(f);
    return *(ushort_t*)&h;
}

// ---------------------------------------------------------------------------
// MFMA bf16 GEMM with split-K: C[M,N] (+)= A[M,K] @ Bt[N,K]^T
// A: f32 row-major (cast to bf16 during LDS staging). Bt: bf16, N x K (pre-
// transposed weights). grid = (N/128, M/64, Z).
// Z==1: C = acc + bias (direct store). Z>1: C pre-init with bias, atomicAdd.
// 256 threads = 4 waves; wave w owns n-range [w*32, w*32+32).
// Per K-step(32): 8 MFMA (4 m-strips x 2 n-tiles), 6 ds_read_b128.
// ---------------------------------------------------------------------------
__global__ __launch_bounds__(256) void gemm_bf16(
    const float* __restrict__ A, int lda,
    const ushort_t* __restrict__ Bt, int ldb,  // ldb == K
    const float* __restrict__ bias,
    float* __restrict__ C, int ldc,
    int M, int N, int K, int kchunk)
{
    const int nb = blockIdx.x, mb = blockIdx.y, zb = blockIdx.z;
    const int k0 = zb * kchunk;
    const int k1 = min(K, k0 + kchunk);
    __shared__ ushort_t As[64][40];    // 64 rows (m) x 32 k, stride 40
    __shared__ ushort_t Bs[128][40];   // 128 rows (n) x 32 k

    const int tid  = threadIdx.x;
    const int wave = tid >> 6;
    const int lane = tid & 63;
    const int quad = lane >> 4;
    const int mrow = lane & 15;

    f32x4 acc[4][2];
    #pragma unroll
    for (int s = 0; s < 4; s++)
        #pragma unroll
        for (int u = 0; u < 2; u++)
            acc[s][u] = (f32x4){0.f, 0.f, 0.f, 0.f};

    // staging indices
    const int arow = tid >> 2, akc = (tid & 3) * 8;        // A: 64 rows x 4 chunks
    const int brow = tid >> 1, bkc = (tid & 1) * 16;       // B: 128 rows x 2 chunks(16)

    for (int kk0 = k0; kk0 < k1; kk0 += 32) {
        // stage A (f32 -> bf16)
        {
            const float* ap = A + (size_t)(mb * 64 + arow) * lda + kk0 + akc;
            float4 v0 = *(const float4*)ap;
            float4 v1 = *(const float4*)(ap + 4);
            us8 w = { f2bf(v0.x), f2bf(v0.y), f2bf(v0.z), f2bf(v0.w),
                      f2bf(v1.x), f2bf(v1.y), f2bf(v1.z), f2bf(v1.w) };
            *(us8*)&As[arow][akc] = w;
        }
        // stage B (bf16 copy, 32 B per thread)
        {
            const ushort_t* bp = Bt + (size_t)(nb * 128 + brow) * ldb + kk0 + bkc;
            *(us8*)&Bs[brow][bkc]     = *(const us8*)bp;
            *(us8*)&Bs[brow][bkc + 8] = *(const us8*)(bp + 8);
        }
        __syncthreads();

        bf16x8 af[4], bfr[2];
        #pragma unroll
        for (int s = 0; s < 4; s++)
            af[s] = *(const bf16x8*)&As[s * 16 + mrow][quad * 8];
        #pragma unroll
        for (int u = 0; u < 2; u++)
            bfr[u] = *(const bf16x8*)&Bs[wave * 32 + u * 16 + mrow][quad * 8];
        #pragma unroll
        for (int s = 0; s < 4; s++)
            #pragma unroll
            for (int u = 0; u < 2; u++)
                acc[s][u] = __builtin_amdgcn_mfma_f32_16x16x32_bf16(
                    af[s], bfr[u], acc[s][u], 0, 0, 0);
        __syncthreads();
    }

    // epilogue: C/D layout row = quad*4+reg, col = lane&15
    if (gridDim.z == 1) {
        #pragma unroll
        for (int s = 0; s < 4; s++) {
            #pragma unroll
            for (int u = 0; u < 2; u++) {
                const int col = nb * 128 + wave * 32 + u * 16 + mrow;
                #pragma unroll
                for (int reg = 0; reg < 4; reg++) {
                    const int row = mb * 64 + s * 16 + quad * 4 + reg;
                    C[(size_t)row * ldc + col] = acc[s][u][reg] + bias[col];
                }
            }
        }
    } else {
        #pragma unroll
        for (int s = 0; s < 4; s++) {
            #pragma unroll
            for (int u = 0; u < 2; u++) {
                const int col = nb * 128 + wave * 32 + u * 16 + mrow;
                #pragma unroll
                for (int reg = 0; reg < 4; reg++) {
                    const int row = mb * 64 + s * 16 + quad * 4 + reg;
                    atomicAdd(&C[(size_t)row * ldc + col], acc[s][u][reg]);
                }
            }
        }
    }
}

// ---------------------------------------------------------------------------
// out[n][k] = bf16(in[k][n]); in: K x N f32, out: N x K bf16. grid(N/32, K/32)
// ---------------------------------------------------------------------------
__global__ __launch_bounds__(256) void transpose_bf16_kernel(
    const float* __restrict__ in, ushort_t* __restrict__ out, int K, int N)
{
    __shared__ float tile[32][33];
    const int k0 = blockIdx.y * 32, n0 = blockIdx.x * 32;
    const int tx = threadIdx.x & 31, ty4 = (threadIdx.x >> 5) * 4;
    #pragma unroll
    for (int i = 0; i < 4; i++)
        tile[ty4 + i][tx] = in[(size_t)(k0 + ty4 + i) * N + n0 + tx];
    __syncthreads();
    #pragma unroll
    for (int i = 0; i < 4; i++)
        out[(size_t)(n0 + ty4 + i) * K + k0 + tx] = f2bf(tile[tx][ty4 + i]);
}

// ---------------------------------------------------------------------------
__global__ void init_bias_kernel(float* __restrict__ C, int ldc,
                                 const float* __restrict__ bias,
                                 int M, int N)
{
    const int gid = blockIdx.x * 256 + threadIdx.x; // over M*N/4
    const int n4 = N >> 2;
    if (gid >= M * n4) return;
    const int m = gid / n4, n = (gid - m * n4) * 4;
    *(float4*)&C[(size_t)m * ldc + n] = *(const float4*)&bias[n];
}

// ---------------------------------------------------------------------------
__global__ void cast_bf16_kernel(const float* __restrict__ src,
                                 __hip_bfloat16* __restrict__ dst, int n)
{
    const int gid = (blockIdx.x * 256 + threadIdx.x) * 4;
    if (gid >= n) return;
    float4 v = *(const float4*)(src + gid);
    dst[gid + 0] = __float2bfloat16(v.x);
    dst[gid + 1] = __float2bfloat16(v.y);
    dst[gid + 2] = __float2bfloat16(v.z);
    dst[gid + 3] = __float2bfloat16(v.w);
}

// ---------------------------------------------------------------------------
__global__ void feats_kernel(const float* __restrict__ emb,
                             const float* __restrict__ Wp,
                             const float* __restrict__ bp,
                             float* __restrict__ f2)
{
    const int gid = blockIdx.x * 256 + threadIdx.x; // 2*S*512
    const int k = gid & 511;
    const int s = (gid >> 9) & (S_ - 1);
    const int c = gid >> 20;
    const float th = 3.14159265358979323846f * (float)s / (float)(S_ - 1);
    f2[gid] = emb[c * 512 + k] + (-sinf(th)) * Wp[k] + cosf(th) * Wp[512 + k] + bp[k];
}

__global__ void init_act_kernel(const float* __restrict__ sa,
                                float* __restrict__ act,
                                float* __restrict__ cat)
{
    const int gid = blockIdx.x * 256 + threadIdx.x; // B*2048
    const int b = gid >> 11, n = gid & 2047;
    const float v = sa[n];
    act[gid] = v;
    cat[(size_t)b * 2560 + 512 + n] = v;
}

__global__ void init_trace_kernel(const float* __restrict__ st,
                                  float* __restrict__ trace)
{
    const int gid = blockIdx.x * 256 + threadIdx.x; // B*2048*25
    trace[gid] = st[gid % (D_MODEL_ * M_)];
}

// ---------------------------------------------------------------------------
__global__ void sync_kernel(const float* __restrict__ act,
                            float* __restrict__ alpha,
                            const float* __restrict__ decay,
                            const int t, const int off,
                            float* __restrict__ sout)
{
    const int b = blockIdx.x;
    const int p = blockIdx.y * 256 + threadIdx.x;
    if (p >= REP_) return;
    int i = 0, rem = p;
    while (rem >= NSY_ - i) { rem -= NSY_ - i; i++; }
    const int j = i + rem;
    const float si = act[(size_t)b * D_MODEL_ + off + i];
    const float sj = act[(size_t)b * D_MODEL_ + off + j];
    const float pair = si * sj;
    const float r = expf(-decay[p]);
    float a;
    if (t == 0) a = pair;
    else        a = r * alpha[(size_t)b * REP_ + p] + pair;
    alpha[(size_t)b * REP_ + p] = a;
    float bta = 1.f;
    for (int k = 0; k < t; k++) bta = r * bta + 1.f;
    sout[(size_t)b * REP_ + p] = a / sqrtf(bta);
}

// ---------------------------------------------------------------------------
__device__ __forceinline__ float bflo(unsigned u) { return __uint_as_float(u << 16); }
__device__ __forceinline__ float bfhi(unsigned u) { return __uint_as_float(u & 0xffff0000u); }

__global__ __launch_bounds__(256) void attn_kernel(
    const float* __restrict__ q,              // (B,512)
    const __hip_bfloat16* __restrict__ Kb,    // (2,S,512) bf16
    const __hip_bfloat16* __restrict__ Vb,    // (2,S,512) bf16
    const int*   __restrict__ tokens,         // (B,S)
    float* __restrict__ o)                    // (B,512)
{
    const int bh = blockIdx.x;
    const int b = bh >> 3, h = bh & 7;
    __shared__ float qs[64];
    __shared__ float sc[S_];
    __shared__ float red[256];
    __shared__ float po[32][68];
    const int tid = threadIdx.x;
    if (tid < 64) qs[tid] = q[(size_t)b * 512 + h * 64 + tid];
    __syncthreads();

    const int* trow = tokens + (size_t)b * S_;

    float lmax = -1e30f;
    #pragma unroll
    for (int i = 0; i < 8; i++) {
        const int s = tid + i * 256;
        const int tok = trow[s];
        const uint4* kp = (const uint4*)(Kb + ((size_t)(tok * S_ + s)) * 512 + h * 64);
        float acc = 0.f;
        #pragma unroll
        for (int j = 0; j < 8; j++) {
            uint4 r = kp[j];
            acc += qs[j*8+0]*bflo(r.x) + qs[j*8+1]*bfhi(r.x)
                 + qs[j*8+2]*bflo(r.y) + qs[j*8+3]*bfhi(r.y)
                 + qs[j*8+4]*bflo(r.z) + qs[j*8+5]*bfhi(r.z)
                 + qs[j*8+6]*bflo(r.w) + qs[j*8+7]*bfhi(r.w);
        }
        acc *= 0.125f;
        sc[s] = acc;
        lmax = fmaxf(lmax, acc);
    }
    red[tid] = lmax; __syncthreads();
    for (int off = 128; off > 0; off >>= 1) {
        if (tid < off) red[tid] = fmaxf(red[tid], red[tid + off]);
        __syncthreads();
    }
    const float mx = red[0];
    __syncthreads();

    float lsum = 0.f;
    #pragma unroll
    for (int i = 0; i < 8; i++) {
        const int s = tid + i * 256;
        const float e = expf(sc[s] - mx);
        sc[s] = e;
        lsum += e;
    }
    red[tid] = lsum; __syncthreads();
    for (int off = 128; off > 0; off >>= 1) {
        if (tid < off) red[tid] += red[tid + off];
        __syncthreads();
    }
    const float inv = 1.f / red[0];
    __syncthreads();

    const int d8 = (tid & 7) * 8;
    const int g  = tid >> 3;
    float va[8] = {};
    #pragma unroll 4
    for (int it = 0; it < 64; it++) {
        const int s = g * 64 + ((it + g) & 63);
        const int tok = trow[s];
        const float p = sc[s];
        uint4 r = *(const uint4*)(Vb + ((size_t)(tok * S_ + s)) * 512 + h * 64 + d8);
        va[0] += p * bflo(r.x); va[1] += p * bfhi(r.x);
        va[2] += p * bflo(r.y); va[3] += p * bfhi(r.y);
        va[4] += p * bflo(r.z); va[5] += p * bfhi(r.z);
        va[6] += p * bflo(r.w); va[7] += p * bfhi(r.w);
    }
    *(float4*)&po[g][d8]     = make_float4(va[0], va[1], va[2], va[3]);
    *(float4*)&po[g][d8 + 4] = make_float4(va[4], va[5], va[6], va[7]);
    __syncthreads();
    if (tid < 64) {
        float acc = 0.f;
        #pragma unroll
        for (int gg = 0; gg < 32; gg++) acc += po[gg][tid];
        o[(size_t)b * 512 + h * 64 + tid] = acc * inv;
    }
}

// ---------------------------------------------------------------------------
__global__ __launch_bounds__(256) void glu_ln_kernel(
    const float* __restrict__ pre,   // (B,4096)
    const float* __restrict__ g,
    const float* __restrict__ bta,
    float* __restrict__ state)       // (B,2048)
{
    const int b = blockIdx.x;
    const int tid = threadIdx.x;
    __shared__ float v[D_MODEL_];
    __shared__ float r1[256], r2[256];
    float s1 = 0.f, s2 = 0.f;
    #pragma unroll
    for (int i = 0; i < 8; i++) {
        const int dd = tid + i * 256;
        const float g1 = pre[(size_t)b * 4096 + dd];
        const float g2 = pre[(size_t)b * 4096 + 2048 + dd];
        const float val = g1 * (1.f / (1.f + expf(-g2)));
        v[dd] = val; s1 += val; s2 += val * val;
    }
    r1[tid] = s1; r2[tid] = s2; __syncthreads();
    for (int off = 128; off > 0; off >>= 1) {
        if (tid < off) { r1[tid] += r1[tid + off]; r2[tid] += r2[tid + off]; }
        __syncthreads();
    }
    const float mu = r1[0] * (1.f / D_MODEL_);
    const float var = fmaxf(r2[0] * (1.f / D_MODEL_) - mu * mu, 0.f);
    const float inv = 1.f / sqrtf(var + 1e-5f);
    #pragma unroll
    for (int i = 0; i < 8; i++) {
        const int dd = tid + i * 256;
        state[(size_t)b * D_MODEL_ + dd] = (v[dd] - mu) * inv * g[dd] + bta[dd];
    }
}

// ---------------------------------------------------------------------------
__global__ void trace_kernel(float* __restrict__ trace,      // (B,2048,25)
                             const float* __restrict__ state,// (B,2048)
                             const float* __restrict__ ln_g, // (25)
                             const float* __restrict__ ln_b, // (25)
                             const float* __restrict__ Wn,   // (25,2,2048)
                             const float* __restrict__ bn,   // (2048,2)
                             const float* __restrict__ temp, // (1)
                             float* __restrict__ act,        // (B,2048)
                             float* __restrict__ cat)        // (B,2560)
{
    const int gid = blockIdx.x * 256 + threadIdx.x; // B*2048
    const int b = gid >> 11, n = gid & 2047;
    float* tr = trace + (size_t)gid * M_;
    float x[M_];
    #pragma unroll
    for (int m = 0; m < M_ - 1; m++) x[m] = tr[m + 1];
    x[M_ - 1] = state[gid];
    #pragma unroll
    for (int m = 0; m < M_; m++) tr[m] = x[m];
    float s1 = 0.f, s2 = 0.f;
    #pragma unroll
    for (int m = 0; m < M_; m++) { s1 += x[m]; s2 += x[m] * x[m]; }
    const float mu = s1 * (1.f / M_);
    const float var = fmaxf(s2 * (1.f / M_) - mu * mu, 0.f);
    const float inv = 1.f / sqrtf(var + 1e-5f);
    float y0 = bn[n * 2 + 0], y1 = bn[n * 2 + 1];
    #pragma unroll
    for (int m = 0; m < M_; m++) {
        const float xn = (x[m] - mu) * inv * ln_g[m] + ln_b[m];
        y0 += xn * Wn[(size_t)(m * 2 + 0) * D_MODEL_ + n];
        y1 += xn * Wn[(size_t)(m * 2 + 1) * D_MODEL_ + n];
    }
    const float a = y0 * (1.f / (1.f + expf(-y1))) / temp[0];
    act[gid] = a;
    cat[(size_t)b * 2560 + 512 + n] = a;
}

// ---------------------------------------------------------------------------
__global__ __launch_bounds__(256) void out_kernel(
    const float* __restrict__ pred,  // (B,4096)
    float* __restrict__ dout,
    const int t)
{
    const int b = blockIdx.x;
    const int tid = threadIdx.x;
    __shared__ float red[256];
    const float* pr = pred + (size_t)b * 4096;
    float sum = 0.f;
    #pragma unroll
    for (int i = 0; i < 8; i++) {
        const int s = tid + i * 256;
        const float l0 = pr[2 * s], l1 = pr[2 * s + 1];
        const float mm = fmaxf(l0, l1);
        const float z0 = expf(l0 - mm), z1 = expf(l1 - mm);
        const float Z = z0 + z1;
        const float lz = logf(Z);
        const float p0 = z0 / Z, p1 = z1 / Z;
        const float lp0 = (l0 - mm) - lz, lp1 = (l1 - mm) - lz;
        sum += -(p0 * lp0 + p1 * lp1) * 1.4426950408889634f;
    }
    red[tid] = sum; __syncthreads();
    for (int off = 128; off > 0; off >>= 1) {
        if (tid < off) red[tid] += red[tid + off];
        __syncthreads();
    }
    #pragma unroll
    for (int i = 0; i < 16; i++) {
        const int jj = tid + i * 256;
        dout[(size_t)(b * 4096 + jj) * T_ + t] = pr[jj];
    }
    if (tid == 0) {
        const float ne = red[0] * (1.f / S_);
        const size_t base = (size_t)B_ * 4096 * T_;
        dout[base + (size_t)(b * 2 + 0) * T_ + t] = ne;
        dout[base + (size_t)(b * 2 + 1) * T_ + t] = 1.f - ne;
    }
}

// ---------------------------------------------------------------------------
extern "C" void kernel_launch(void* const* d_in, const int* in_sizes, int n_in,
                              void* d_out, int out_size, void* d_ws, size_t ws_size,
                              hipStream_t stream)
{
    const int*   tokens    = (const int*)  d_in[0];
    const float* emb       = (const float*)d_in[1];
    const float* W_pos     = (const float*)d_in[2];
    const float* b_pos     = (const float*)d_in[3];
    const float* Wq        = (const float*)d_in[4];
    const float* bq        = (const float*)d_in[5];
    const float* Wk        = (const float*)d_in[6];
    const float* bk        = (const float*)d_in[7];
    const float* Wv        = (const float*)d_in[8];
    const float* bv        = (const float*)d_in[9];
    const float* Wo        = (const float*)d_in[10];
    const float* bo        = (const float*)d_in[11];
    const float* Ws        = (const float*)d_in[12];
    const float* bs        = (const float*)d_in[13];
    const float* ln_s_g    = (const float*)d_in[14];
    const float* ln_s_b    = (const float*)d_in[15];
    const float* ln_n_g    = (const float*)d_in[16];
    const float* ln_n_b    = (const float*)d_in[17];
    const float* Wn        = (const float*)d_in[18];
    const float* bn        = (const float*)d_in[19];
    const float* temp      = (const float*)d_in[20];
    const float* Wout      = (const float*)d_in[21];
    const float* bout      = (const float*)d_in[22];
    const float* start_act = (const float*)d_in[23];
    const float* start_tr  = (const float*)d_in[24];
    const float* dec_act   = (const float*)d_in[25];
    const float* dec_out   = (const float*)d_in[26];
    float* out = (float*)d_out;
    float* w = (float*)d_ws;

    // workspace layout (floats)
    size_t off = 0;
    float* f2     = w + off; off += (size_t)2 * S_ * 512;
    float* Ktab   = w + off; off += (size_t)2 * S_ * 512;
    float* Vtab   = w + off; off += (size_t)2 * S_ * 512;
    float* act    = w + off; off += (size_t)B_ * D_MODEL_;
    float* cat    = w + off; off += (size_t)B_ * 2560;
    float* a_a    = w + off; off += (size_t)B_ * REP_;
    float* a_o    = w + off; off += (size_t)B_ * REP_;
    float* s_act  = w + off; off += (size_t)B_ * REP_;
    float* s_out  = w + off; off += (size_t)B_ * REP_;
    float* qbuf   = w + off; off += (size_t)B_ * 512;
    float* o_attn = w + off; off += (size_t)B_ * 512;
    float* pre    = w + off; off += (size_t)B_ * 4096;
    float* state  = w + off; off += (size_t)B_ * D_MODEL_;
    float* trace  = w + off; off += (size_t)B_ * D_MODEL_ * M_;
    float* predb  = w + off; off += (size_t)B_ * 4096;
    __hip_bfloat16* Kb = (__hip_bfloat16*)(w + off); off += (size_t)S_ * 512;
    __hip_bfloat16* Vb = (__hip_bfloat16*)(w + off); off += (size_t)S_ * 512;
    // transposed bf16 weights (N x K each); sizes in ushort, round up to floats
    ushort_t* WkT   = (ushort_t*)(w + off); off += (size_t)512 * 512 / 2;
    ushort_t* WvT   = (ushort_t*)(w + off); off += (size_t)512 * 512 / 2;
    ushort_t* WqT   = (ushort_t*)(w + off); off += (size_t)512 * REP_ / 2;
    ushort_t* WoT   = (ushort_t*)(w + off); off += (size_t)512 * 512 / 2;
    ushort_t* WsT   = (ushort_t*)(w + off); off += (size_t)4096 * 2560 / 2;
    ushort_t* WoutT = (ushort_t*)(w + off); off += (size_t)4096 * REP_ / 2;

    // ---- pre-loop ----
    feats_kernel<<<(2 * S_ * 512) / 256, 256, 0, stream>>>(emb, W_pos, b_pos, f2);
    init_act_kernel<<<(B_ * D_MODEL_) / 256, 256, 0, stream>>>(start_act, act, cat);
    init_trace_kernel<<<(B_ * D_MODEL_ * M_) / 256, 256, 0, stream>>>(start_tr, trace);

    // weight transposes (K x N -> N x K bf16)
    transpose_bf16_kernel<<<dim3(512 / 32, 512 / 32), 256, 0, stream>>>(Wk, WkT, 512, 512);
    transpose_bf16_kernel<<<dim3(512 / 32, 512 / 32), 256, 0, stream>>>(Wv, WvT, 512, 512);
    transpose_bf16_kernel<<<dim3(512 / 32, REP_ / 32), 256, 0, stream>>>(Wq, WqT, REP_, 512);
    transpose_bf16_kernel<<<dim3(512 / 32, 512 / 32), 256, 0, stream>>>(Wo, WoT, 512, 512);
    transpose_bf16_kernel<<<dim3(4096 / 32, 2560 / 32), 256, 0, stream>>>(Ws, WsT, 2560, 4096);
    transpose_bf16_kernel<<<dim3(4096 / 32, REP_ / 32), 256, 0, stream>>>(Wout, WoutT, REP_, 4096);

    // Ktab/Vtab: M=4096, N=512, K=512, Z=1 direct store (grid 4 x 64)
    gemm_bf16<<<dim3(512 / 128, (2 * S_) / 64, 1), 256, 0, stream>>>(
        f2, 512, WkT, 512, bk, Ktab, 512, 2 * S_, 512, 512, 512);
    gemm_bf16<<<dim3(512 / 128, (2 * S_) / 64, 1), 256, 0, stream>>>(
        f2, 512, WvT, 512, bv, Vtab, 512, 2 * S_, 512, 512, 512);
    cast_bf16_kernel<<<(2 * S_ * 512 / 4) / 256, 256, 0, stream>>>(Ktab, Kb, 2 * S_ * 512);
    cast_bf16_kernel<<<(2 * S_ * 512 / 4) / 256, 256, 0, stream>>>(Vtab, Vb, 2 * S_ * 512);

    // ---- T iterations ----
    for (int t = 0; t < T_; t++) {
        sync_kernel<<<dim3(B_, 9), 256, 0, stream>>>(act, a_a, dec_act, t, D_MODEL_ - NSY_, s_act);

        // q = s_act @ Wq + bq : M=128,N=512,K=2080; Z=13, kchunk=160 -> 104 blocks
        init_bias_kernel<<<(B_ * 512 / 4 + 255) / 256, 256, 0, stream>>>(qbuf, 512, bq, B_, 512);
        gemm_bf16<<<dim3(512 / 128, 2, 13), 256, 0, stream>>>(
            s_act, REP_, WqT, REP_, bq, qbuf, 512, B_, 512, REP_, 160);

        attn_kernel<<<B_ * H_, 256, 0, stream>>>(qbuf, Kb, Vb, tokens, o_attn);

        // o_proj -> cat[:, :512] : K=512; Z=8, kchunk=64 -> 64 blocks
        init_bias_kernel<<<(B_ * 512 / 4 + 255) / 256, 256, 0, stream>>>(cat, 2560, bo, B_, 512);
        gemm_bf16<<<dim3(512 / 128, 2, 8), 256, 0, stream>>>(
            o_attn, 512, WoT, 512, bo, cat, 2560, B_, 512, 512, 64);

        // pre = cat @ Ws + bs : N=4096,K=2560; Z=8, kchunk=320 -> 512 blocks
        init_bias_kernel<<<(B_ * 4096 / 4 + 255) / 256, 256, 0, stream>>>(pre, 4096, bs, B_, 4096);
        gemm_bf16<<<dim3(4096 / 128, 2, 8), 256, 0, stream>>>(
            cat, 2560, WsT, 2560, bs, pre, 4096, B_, 4096, 2560, 320);

        glu_ln_kernel<<<B_, 256, 0, stream>>>(pre, ln_s_g, ln_s_b, state);
        trace_kernel<<<(B_ * D_MODEL_) / 256, 256, 0, stream>>>(
            trace, state, ln_n_g, ln_n_b, Wn, bn, temp, act, cat);

        sync_kernel<<<dim3(B_, 9), 256, 0, stream>>>(act, a_o, dec_out, t, 0, s_out);

        // pred = s_out @ Wout + bout : N=4096,K=2080; Z=5, kchunk=416 -> 320 blocks
        init_bias_kernel<<<(B_ * 4096 / 4 + 255) / 256, 256, 0, stream>>>(predb, 4096, bout, B_, 4096);
        gemm_bf16<<<dim3(4096 / 128, 2, 5), 256, 0, stream>>>(
            s_out, REP_, WoutT, REP_, bout, predb, 4096, B_, 4096, REP_, 416);

        out_kernel<<<B_, 256, 0, stream>>>(predb, out, t);
    }
}

// Round 5
// 1609.292 us; speedup vs baseline: 3.7171x; 1.1175x over previous
//
#include <hip/hip_runtime.h>
#include <hip/hip_bf16.h>
#include <math.h>

#define B_ 128
#define S_ 2048
#define D_IN_ 512
#define D_MODEL_ 2048
#define M_ 25
#define NSY_ 64
#define H_ 8
#define T_ 10
#define REP_ 2080
#define DH_ 64

typedef unsigned short ushort_t;
typedef __bf16 bf16x8 __attribute__((ext_vector_type(8)));
typedef float f32x4 __attribute__((ext_vector_type(4)));
typedef unsigned short us8 __attribute__((ext_vector_type(8)));

__device__ __forceinline__ ushort_t f2bf(float f) {
    __hip_bfloat16 h = __float2bfloat16(f);
    return *(ushort_t*)&h;
}
__device__ __forceinline__ float bflo(unsigned u) { return __uint_as_float(u << 16); }
__device__ __forceinline__ float bfhi(unsigned u) { return __uint_as_float(u & 0xffff0000u); }

// ---------------------------------------------------------------------------
// MFMA bf16 GEMM with split-K: C[M,N] (+)= A[M,K] @ Bt[N,K]^T
// A: f32 row-major (cast to bf16 during LDS staging). Bt: bf16, N x K.
// grid = (N/128, M/64, Z). Z==1: C = acc + bias. Z>1: atomicAdd partials.
// ---------------------------------------------------------------------------
__global__ __launch_bounds__(256) void gemm_bf16(
    const float* __restrict__ A, int lda,
    const ushort_t* __restrict__ Bt, int ldb,  // ldb == K
    const float* __restrict__ bias,
    float* __restrict__ C, int ldc,
    int M, int N, int K, int kchunk)
{
    const int nb = blockIdx.x, mb = blockIdx.y, zb = blockIdx.z;
    const int k0 = zb * kchunk;
    const int k1 = min(K, k0 + kchunk);
    __shared__ ushort_t As[64][40];
    __shared__ ushort_t Bs[128][40];

    const int tid  = threadIdx.x;
    const int wave = tid >> 6;
    const int lane = tid & 63;
    const int quad = lane >> 4;
    const int mrow = lane & 15;

    f32x4 acc[4][2];
    #pragma unroll
    for (int s = 0; s < 4; s++)
        #pragma unroll
        for (int u = 0; u < 2; u++)
            acc[s][u] = (f32x4){0.f, 0.f, 0.f, 0.f};

    const int arow = tid >> 2, akc = (tid & 3) * 8;
    const int brow = tid >> 1, bkc = (tid & 1) * 16;

    for (int kk0 = k0; kk0 < k1; kk0 += 32) {
        {
            const float* ap = A + (size_t)(mb * 64 + arow) * lda + kk0 + akc;
            float4 v0 = *(const float4*)ap;
            float4 v1 = *(const float4*)(ap + 4);
            us8 w = { f2bf(v0.x), f2bf(v0.y), f2bf(v0.z), f2bf(v0.w),
                      f2bf(v1.x), f2bf(v1.y), f2bf(v1.z), f2bf(v1.w) };
            *(us8*)&As[arow][akc] = w;
        }
        {
            const ushort_t* bp = Bt + (size_t)(nb * 128 + brow) * ldb + kk0 + bkc;
            *(us8*)&Bs[brow][bkc]     = *(const us8*)bp;
            *(us8*)&Bs[brow][bkc + 8] = *(const us8*)(bp + 8);
        }
        __syncthreads();

        bf16x8 af[4], bfr[2];
        #pragma unroll
        for (int s = 0; s < 4; s++)
            af[s] = *(const bf16x8*)&As[s * 16 + mrow][quad * 8];
        #pragma unroll
        for (int u = 0; u < 2; u++)
            bfr[u] = *(const bf16x8*)&Bs[wave * 32 + u * 16 + mrow][quad * 8];
        #pragma unroll
        for (int s = 0; s < 4; s++)
            #pragma unroll
            for (int u = 0; u < 2; u++)
                acc[s][u] = __builtin_amdgcn_mfma_f32_16x16x32_bf16(
                    af[s], bfr[u], acc[s][u], 0, 0, 0);
        __syncthreads();
    }

    if (gridDim.z == 1) {
        #pragma unroll
        for (int s = 0; s < 4; s++) {
            #pragma unroll
            for (int u = 0; u < 2; u++) {
                const int col = nb * 128 + wave * 32 + u * 16 + mrow;
                #pragma unroll
                for (int reg = 0; reg < 4; reg++) {
                    const int row = mb * 64 + s * 16 + quad * 4 + reg;
                    C[(size_t)row * ldc + col] = acc[s][u][reg] + bias[col];
                }
            }
        }
    } else {
        #pragma unroll
        for (int s = 0; s < 4; s++) {
            #pragma unroll
            for (int u = 0; u < 2; u++) {
                const int col = nb * 128 + wave * 32 + u * 16 + mrow;
                #pragma unroll
                for (int reg = 0; reg < 4; reg++) {
                    const int row = mb * 64 + s * 16 + quad * 4 + reg;
                    atomicAdd(&C[(size_t)row * ldc + col], acc[s][u][reg]);
                }
            }
        }
    }
}

// ---------------------------------------------------------------------------
// QK scores, dense both-token variant:
// sc[(c*8+h)*128 + b][s] = 0.125 * sum_d q[b, h*64+d] * Kb[c*S+s, h*64+d]
// grid = (S/128, B/64, 16=c*8+h). Same tile structure as gemm_bf16, K=64.
// ---------------------------------------------------------------------------
__global__ __launch_bounds__(256) void gemm_qk(
    const float* __restrict__ q,          // (B,512)
    const ushort_t* __restrict__ Kb,      // (2,S,512) bf16
    float* __restrict__ sc)               // (16,128,2048)
{
    const int nb = blockIdx.x, mb = blockIdx.y, z = blockIdx.z;
    const int c = z >> 3, h = z & 7;
    __shared__ ushort_t As[64][40];
    __shared__ ushort_t Bs[128][40];

    const int tid  = threadIdx.x;
    const int wave = tid >> 6;
    const int lane = tid & 63;
    const int quad = lane >> 4;
    const int mrow = lane & 15;

    f32x4 acc[4][2];
    #pragma unroll
    for (int s = 0; s < 4; s++)
        #pragma unroll
        for (int u = 0; u < 2; u++)
            acc[s][u] = (f32x4){0.f, 0.f, 0.f, 0.f};

    const int arow = tid >> 2, akc = (tid & 3) * 8;
    const int brow = tid >> 1, bkc = (tid & 1) * 16;
    const float* Abase = q + (size_t)h * 64;
    const ushort_t* Bbase = Kb + (size_t)c * S_ * 512 + h * 64;

    #pragma unroll
    for (int kk0 = 0; kk0 < 64; kk0 += 32) {
        {
            const float* ap = Abase + (size_t)(mb * 64 + arow) * 512 + kk0 + akc;
            float4 v0 = *(const float4*)ap;
            float4 v1 = *(const float4*)(ap + 4);
            us8 w = { f2bf(v0.x), f2bf(v0.y), f2bf(v0.z), f2bf(v0.w),
                      f2bf(v1.x), f2bf(v1.y), f2bf(v1.z), f2bf(v1.w) };
            *(us8*)&As[arow][akc] = w;
        }
        {
            const ushort_t* bp = Bbase + (size_t)(nb * 128 + brow) * 512 + kk0 + bkc;
            *(us8*)&Bs[brow][bkc]     = *(const us8*)bp;
            *(us8*)&Bs[brow][bkc + 8] = *(const us8*)(bp + 8);
        }
        __syncthreads();

        bf16x8 af[4], bfr[2];
        #pragma unroll
        for (int s = 0; s < 4; s++)
            af[s] = *(const bf16x8*)&As[s * 16 + mrow][quad * 8];
        #pragma unroll
        for (int u = 0; u < 2; u++)
            bfr[u] = *(const bf16x8*)&Bs[wave * 32 + u * 16 + mrow][quad * 8];
        #pragma unroll
        for (int s = 0; s < 4; s++)
            #pragma unroll
            for (int u = 0; u < 2; u++)
                acc[s][u] = __builtin_amdgcn_mfma_f32_16x16x32_bf16(
                    af[s], bfr[u], acc[s][u], 0, 0, 0);
        __syncthreads();
    }

    float* Cb = sc + (size_t)z * 128 * S_;
    #pragma unroll
    for (int s = 0; s < 4; s++) {
        #pragma unroll
        for (int u = 0; u < 2; u++) {
            const int col = nb * 128 + wave * 32 + u * 16 + mrow;
            #pragma unroll
            for (int reg = 0; reg < 4; reg++) {
                const int row = mb * 64 + s * 16 + quad * 4 + reg;
                Cb[(size_t)row * S_ + col] = 0.125f * acc[s][u][reg];
            }
        }
    }
}

// ---------------------------------------------------------------------------
// Fused token-select + softmax + dense dual-V pass. One block per (b,h).
// sc layout: (c*8+h, b, s). V dense reads of both token tables.
// ---------------------------------------------------------------------------
__global__ __launch_bounds__(256) void attn_pv(
    const float* __restrict__ sc,             // (16,128,2048)
    const __hip_bfloat16* __restrict__ Vb,    // (2,S,512) bf16
    const int*   __restrict__ tokens,         // (B,S)
    float* __restrict__ o)                    // (B,512)
{
    const int bh = blockIdx.x;
    const int b = bh >> 3, h = bh & 7;
    __shared__ float ps[S_][2];    // interleaved p0,p1
    __shared__ float red[256];
    __shared__ float po[32][68];
    const int tid = threadIdx.x;

    const float* sc0 = sc + ((size_t)h * 128 + b) * S_;
    const float* sc1 = sc + ((size_t)(8 + h) * 128 + b) * S_;
    const int* trow = tokens + (size_t)b * S_;

    // select + max
    float lmax = -1e30f;
    int tok[8];
    float sel[8];
    #pragma unroll
    for (int i = 0; i < 8; i++) {
        const int s = tid + i * 256;
        tok[i] = trow[s];
        sel[i] = tok[i] ? sc1[s] : sc0[s];
        lmax = fmaxf(lmax, sel[i]);
    }
    red[tid] = lmax; __syncthreads();
    for (int off = 128; off > 0; off >>= 1) {
        if (tid < off) red[tid] = fmaxf(red[tid], red[tid + off]);
        __syncthreads();
    }
    const float mx = red[0];
    __syncthreads();

    // exp + scatter into p0/p1
    float lsum = 0.f;
    #pragma unroll
    for (int i = 0; i < 8; i++) {
        const int s = tid + i * 256;
        const float e = expf(sel[i] - mx);
        lsum += e;
        ps[s][0] = tok[i] ? 0.f : e;
        ps[s][1] = tok[i] ? e : 0.f;
    }
    red[tid] = lsum; __syncthreads();
    for (int off = 128; off > 0; off >>= 1) {
        if (tid < off) red[tid] += red[tid + off];
        __syncthreads();
    }
    const float inv = 1.f / red[0];

    // dense dual-V pass: 32 s-groups x 8 dims/thread
    const int d8 = (tid & 7) * 8;
    const int g  = tid >> 3;
    const __hip_bfloat16* V0 = Vb + (size_t)h * 64 + d8;
    const __hip_bfloat16* V1 = V0 + (size_t)S_ * 512;
    float va[8] = {};
    #pragma unroll 4
    for (int it = 0; it < 64; it++) {
        const int s = g * 64 + ((it + g * 4) & 63);   // 8 groups -> 8 distinct banks
        const float p0 = ps[s][0];
        const float p1 = ps[s][1];
        uint4 r0 = *(const uint4*)(V0 + (size_t)s * 512);
        uint4 r1 = *(const uint4*)(V1 + (size_t)s * 512);
        va[0] += p0 * bflo(r0.x) + p1 * bflo(r1.x);
        va[1] += p0 * bfhi(r0.x) + p1 * bfhi(r1.x);
        va[2] += p0 * bflo(r0.y) + p1 * bflo(r1.y);
        va[3] += p0 * bfhi(r0.y) + p1 * bfhi(r1.y);
        va[4] += p0 * bflo(r0.z) + p1 * bflo(r1.z);
        va[5] += p0 * bfhi(r0.z) + p1 * bfhi(r1.z);
        va[6] += p0 * bflo(r0.w) + p1 * bflo(r1.w);
        va[7] += p0 * bfhi(r0.w) + p1 * bfhi(r1.w);
    }
    *(float4*)&po[g][d8]     = make_float4(va[0], va[1], va[2], va[3]);
    *(float4*)&po[g][d8 + 4] = make_float4(va[4], va[5], va[6], va[7]);
    __syncthreads();
    if (tid < 64) {
        float acc = 0.f;
        #pragma unroll
        for (int gg = 0; gg < 32; gg++) acc += po[gg][tid];
        o[(size_t)b * 512 + h * 64 + tid] = acc * inv;
    }
}

// ---------------------------------------------------------------------------
// out[n][k] = bf16(in[k][n]); in: K x N f32. grid(N/32, K/32)
// ---------------------------------------------------------------------------
__global__ __launch_bounds__(256) void transpose_bf16_kernel(
    const float* __restrict__ in, ushort_t* __restrict__ out, int K, int N)
{
    __shared__ float tile[32][33];
    const int k0 = blockIdx.y * 32, n0 = blockIdx.x * 32;
    const int tx = threadIdx.x & 31, ty4 = (threadIdx.x >> 5) * 4;
    #pragma unroll
    for (int i = 0; i < 4; i++)
        tile[ty4 + i][tx] = in[(size_t)(k0 + ty4 + i) * N + n0 + tx];
    __syncthreads();
    #pragma unroll
    for (int i = 0; i < 4; i++)
        out[(size_t)(n0 + ty4 + i) * K + k0 + tx] = f2bf(tile[tx][ty4 + i]);
}

// ---------------------------------------------------------------------------
__global__ void init_bias_kernel(float* __restrict__ C, int ldc,
                                 const float* __restrict__ bias,
                                 int M, int N)
{
    const int gid = blockIdx.x * 256 + threadIdx.x;
    const int n4 = N >> 2;
    if (gid >= M * n4) return;
    const int m = gid / n4, n = (gid - m * n4) * 4;
    *(float4*)&C[(size_t)m * ldc + n] = *(const float4*)&bias[n];
}

// ---------------------------------------------------------------------------
__global__ void cast_bf16_kernel(const float* __restrict__ src,
                                 __hip_bfloat16* __restrict__ dst, int n)
{
    const int gid = (blockIdx.x * 256 + threadIdx.x) * 4;
    if (gid >= n) return;
    float4 v = *(const float4*)(src + gid);
    dst[gid + 0] = __float2bfloat16(v.x);
    dst[gid + 1] = __float2bfloat16(v.y);
    dst[gid + 2] = __float2bfloat16(v.z);
    dst[gid + 3] = __float2bfloat16(v.w);
}

// ---------------------------------------------------------------------------
__global__ void feats_kernel(const float* __restrict__ emb,
                             const float* __restrict__ Wp,
                             const float* __restrict__ bp,
                             float* __restrict__ f2)
{
    const int gid = blockIdx.x * 256 + threadIdx.x;
    const int k = gid & 511;
    const int s = (gid >> 9) & (S_ - 1);
    const int c = gid >> 20;
    const float th = 3.14159265358979323846f * (float)s / (float)(S_ - 1);
    f2[gid] = emb[c * 512 + k] + (-sinf(th)) * Wp[k] + cosf(th) * Wp[512 + k] + bp[k];
}

__global__ void init_act_kernel(const float* __restrict__ sa,
                                float* __restrict__ act,
                                float* __restrict__ cat)
{
    const int gid = blockIdx.x * 256 + threadIdx.x;
    const int b = gid >> 11, n = gid & 2047;
    const float v = sa[n];
    act[gid] = v;
    cat[(size_t)b * 2560 + 512 + n] = v;
}

__global__ void init_trace_kernel(const float* __restrict__ st,
                                  float* __restrict__ trace)
{
    const int gid = blockIdx.x * 256 + threadIdx.x;
    trace[gid] = st[gid % (D_MODEL_ * M_)];
}

// ---------------------------------------------------------------------------
__global__ void sync_kernel(const float* __restrict__ act,
                            float* __restrict__ alpha,
                            const float* __restrict__ decay,
                            const int t, const int off,
                            float* __restrict__ sout)
{
    const int b = blockIdx.x;
    const int p = blockIdx.y * 256 + threadIdx.x;
    if (p >= REP_) return;
    int i = 0, rem = p;
    while (rem >= NSY_ - i) { rem -= NSY_ - i; i++; }
    const int j = i + rem;
    const float si = act[(size_t)b * D_MODEL_ + off + i];
    const float sj = act[(size_t)b * D_MODEL_ + off + j];
    const float pair = si * sj;
    const float r = expf(-decay[p]);
    float a;
    if (t == 0) a = pair;
    else        a = r * alpha[(size_t)b * REP_ + p] + pair;
    alpha[(size_t)b * REP_ + p] = a;
    float bta = 1.f;
    for (int k = 0; k < t; k++) bta = r * bta + 1.f;
    sout[(size_t)b * REP_ + p] = a / sqrtf(bta);
}

// ---------------------------------------------------------------------------
__global__ __launch_bounds__(256) void glu_ln_kernel(
    const float* __restrict__ pre,   // (B,4096)
    const float* __restrict__ g,
    const float* __restrict__ bta,
    float* __restrict__ state)       // (B,2048)
{
    const int b = blockIdx.x;
    const int tid = threadIdx.x;
    __shared__ float v[D_MODEL_];
    __shared__ float r1[256], r2[256];
    float s1 = 0.f, s2 = 0.f;
    #pragma unroll
    for (int i = 0; i < 8; i++) {
        const int dd = tid + i * 256;
        const float g1 = pre[(size_t)b * 4096 + dd];
        const float g2 = pre[(size_t)b * 4096 + 2048 + dd];
        const float val = g1 * (1.f / (1.f + expf(-g2)));
        v[dd] = val; s1 += val; s2 += val * val;
    }
    r1[tid] = s1; r2[tid] = s2; __syncthreads();
    for (int off = 128; off > 0; off >>= 1) {
        if (tid < off) { r1[tid] += r1[tid + off]; r2[tid] += r2[tid + off]; }
        __syncthreads();
    }
    const float mu = r1[0] * (1.f / D_MODEL_);
    const float var = fmaxf(r2[0] * (1.f / D_MODEL_) - mu * mu, 0.f);
    const float inv = 1.f / sqrtf(var + 1e-5f);
    #pragma unroll
    for (int i = 0; i < 8; i++) {
        const int dd = tid + i * 256;
        state[(size_t)b * D_MODEL_ + dd] = (v[dd] - mu) * inv * g[dd] + bta[dd];
    }
}

// ---------------------------------------------------------------------------
__global__ void trace_kernel(float* __restrict__ trace,      // (B,2048,25)
                             const float* __restrict__ state,// (B,2048)
                             const float* __restrict__ ln_g, // (25)
                             const float* __restrict__ ln_b, // (25)
                             const float* __restrict__ Wn,   // (25,2,2048)
                             const float* __restrict__ bn,   // (2048,2)
                             const float* __restrict__ temp, // (1)
                             float* __restrict__ act,        // (B,2048)
                             float* __restrict__ cat)        // (B,2560)
{
    const int gid = blockIdx.x * 256 + threadIdx.x;
    const int b = gid >> 11, n = gid & 2047;
    float* tr = trace + (size_t)gid * M_;
    float x[M_];
    #pragma unroll
    for (int m = 0; m < M_ - 1; m++) x[m] = tr[m + 1];
    x[M_ - 1] = state[gid];
    #pragma unroll
    for (int m = 0; m < M_; m++) tr[m] = x[m];
    float s1 = 0.f, s2 = 0.f;
    #pragma unroll
    for (int m = 0; m < M_; m++) { s1 += x[m]; s2 += x[m] * x[m]; }
    const float mu = s1 * (1.f / M_);
    const float var = fmaxf(s2 * (1.f / M_) - mu * mu, 0.f);
    const float inv = 1.f / sqrtf(var + 1e-5f);
    float y0 = bn[n * 2 + 0], y1 = bn[n * 2 + 1];
    #pragma unroll
    for (int m = 0; m < M_; m++) {
        const float xn = (x[m] - mu) * inv * ln_g[m] + ln_b[m];
        y0 += xn * Wn[(size_t)(m * 2 + 0) * D_MODEL_ + n];
        y1 += xn * Wn[(size_t)(m * 2 + 1) * D_MODEL_ + n];
    }
    const float a = y0 * (1.f / (1.f + expf(-y1))) / temp[0];
    act[gid] = a;
    cat[(size_t)b * 2560 + 512 + n] = a;
}

// ---------------------------------------------------------------------------
__global__ __launch_bounds__(256) void out_kernel(
    const float* __restrict__ pred,  // (B,4096)
    float* __restrict__ dout,
    const int t)
{
    const int b = blockIdx.x;
    const int tid = threadIdx.x;
    __shared__ float red[256];
    const float* pr = pred + (size_t)b * 4096;
    float sum = 0.f;
    #pragma unroll
    for (int i = 0; i < 8; i++) {
        const int s = tid + i * 256;
        const float l0 = pr[2 * s], l1 = pr[2 * s + 1];
        const float mm = fmaxf(l0, l1);
        const float z0 = expf(l0 - mm), z1 = expf(l1 - mm);
        const float Z = z0 + z1;
        const float lz = logf(Z);
        const float p0 = z0 / Z, p1 = z1 / Z;
        const float lp0 = (l0 - mm) - lz, lp1 = (l1 - mm) - lz;
        sum += -(p0 * lp0 + p1 * lp1) * 1.4426950408889634f;
    }
    red[tid] = sum; __syncthreads();
    for (int off = 128; off > 0; off >>= 1) {
        if (tid < off) red[tid] += red[tid + off];
        __syncthreads();
    }
    #pragma unroll
    for (int i = 0; i < 16; i++) {
        const int jj = tid + i * 256;
        dout[(size_t)(b * 4096 + jj) * T_ + t] = pr[jj];
    }
    if (tid == 0) {
        const float ne = red[0] * (1.f / S_);
        const size_t base = (size_t)B_ * 4096 * T_;
        dout[base + (size_t)(b * 2 + 0) * T_ + t] = ne;
        dout[base + (size_t)(b * 2 + 1) * T_ + t] = 1.f - ne;
    }
}

// ---------------------------------------------------------------------------
extern "C" void kernel_launch(void* const* d_in, const int* in_sizes, int n_in,
                              void* d_out, int out_size, void* d_ws, size_t ws_size,
                              hipStream_t stream)
{
    const int*   tokens    = (const int*)  d_in[0];
    const float* emb       = (const float*)d_in[1];
    const float* W_pos     = (const float*)d_in[2];
    const float* b_pos     = (const float*)d_in[3];
    const float* Wq        = (const float*)d_in[4];
    const float* bq        = (const float*)d_in[5];
    const float* Wk        = (const float*)d_in[6];
    const float* bk        = (const float*)d_in[7];
    const float* Wv        = (const float*)d_in[8];
    const float* bv        = (const float*)d_in[9];
    const float* Wo        = (const float*)d_in[10];
    const float* bo        = (const float*)d_in[11];
    const float* Ws        = (const float*)d_in[12];
    const float* bs        = (const float*)d_in[13];
    const float* ln_s_g    = (const float*)d_in[14];
    const float* ln_s_b    = (const float*)d_in[15];
    const float* ln_n_g    = (const float*)d_in[16];
    const float* ln_n_b    = (const float*)d_in[17];
    const float* Wn        = (const float*)d_in[18];
    const float* bn        = (const float*)d_in[19];
    const float* temp      = (const float*)d_in[20];
    const float* Wout      = (const float*)d_in[21];
    const float* bout      = (const float*)d_in[22];
    const float* start_act = (const float*)d_in[23];
    const float* start_tr  = (const float*)d_in[24];
    const float* dec_act   = (const float*)d_in[25];
    const float* dec_out   = (const float*)d_in[26];
    float* out = (float*)d_out;
    float* w = (float*)d_ws;

    // workspace layout (floats)
    size_t off = 0;
    float* f2     = w + off; off += (size_t)2 * S_ * 512;
    float* Ktab   = w + off; off += (size_t)2 * S_ * 512;
    float* Vtab   = w + off; off += (size_t)2 * S_ * 512;
    float* act    = w + off; off += (size_t)B_ * D_MODEL_;
    float* cat    = w + off; off += (size_t)B_ * 2560;
    float* a_a    = w + off; off += (size_t)B_ * REP_;
    float* a_o    = w + off; off += (size_t)B_ * REP_;
    float* s_act  = w + off; off += (size_t)B_ * REP_;
    float* s_out  = w + off; off += (size_t)B_ * REP_;
    float* qbuf   = w + off; off += (size_t)B_ * 512;
    float* o_attn = w + off; off += (size_t)B_ * 512;
    float* pre    = w + off; off += (size_t)B_ * 4096;
    float* state  = w + off; off += (size_t)B_ * D_MODEL_;
    float* trace  = w + off; off += (size_t)B_ * D_MODEL_ * M_;
    float* predb  = w + off; off += (size_t)B_ * 4096;
    float* scbuf  = w + off; off += (size_t)16 * 128 * S_;   // 4.19M floats
    __hip_bfloat16* Kb = (__hip_bfloat16*)(w + off); off += (size_t)S_ * 512;
    __hip_bfloat16* Vb = (__hip_bfloat16*)(w + off); off += (size_t)S_ * 512;
    ushort_t* WkT   = (ushort_t*)(w + off); off += (size_t)512 * 512 / 2;
    ushort_t* WvT   = (ushort_t*)(w + off); off += (size_t)512 * 512 / 2;
    ushort_t* WqT   = (ushort_t*)(w + off); off += (size_t)512 * REP_ / 2;
    ushort_t* WoT   = (ushort_t*)(w + off); off += (size_t)512 * 512 / 2;
    ushort_t* WsT   = (ushort_t*)(w + off); off += (size_t)4096 * 2560 / 2;
    ushort_t* WoutT = (ushort_t*)(w + off); off += (size_t)4096 * REP_ / 2;

    // ---- pre-loop ----
    feats_kernel<<<(2 * S_ * 512) / 256, 256, 0, stream>>>(emb, W_pos, b_pos, f2);
    init_act_kernel<<<(B_ * D_MODEL_) / 256, 256, 0, stream>>>(start_act, act, cat);
    init_trace_kernel<<<(B_ * D_MODEL_ * M_) / 256, 256, 0, stream>>>(start_tr, trace);

    transpose_bf16_kernel<<<dim3(512 / 32, 512 / 32), 256, 0, stream>>>(Wk, WkT, 512, 512);
    transpose_bf16_kernel<<<dim3(512 / 32, 512 / 32), 256, 0, stream>>>(Wv, WvT, 512, 512);
    transpose_bf16_kernel<<<dim3(512 / 32, REP_ / 32), 256, 0, stream>>>(Wq, WqT, REP_, 512);
    transpose_bf16_kernel<<<dim3(512 / 32, 512 / 32), 256, 0, stream>>>(Wo, WoT, 512, 512);
    transpose_bf16_kernel<<<dim3(4096 / 32, 2560 / 32), 256, 0, stream>>>(Ws, WsT, 2560, 4096);
    transpose_bf16_kernel<<<dim3(4096 / 32, REP_ / 32), 256, 0, stream>>>(Wout, WoutT, REP_, 4096);

    gemm_bf16<<<dim3(512 / 128, (2 * S_) / 64, 1), 256, 0, stream>>>(
        f2, 512, WkT, 512, bk, Ktab, 512, 2 * S_, 512, 512, 512);
    gemm_bf16<<<dim3(512 / 128, (2 * S_) / 64, 1), 256, 0, stream>>>(
        f2, 512, WvT, 512, bv, Vtab, 512, 2 * S_, 512, 512, 512);
    cast_bf16_kernel<<<(2 * S_ * 512 / 4) / 256, 256, 0, stream>>>(Ktab, Kb, 2 * S_ * 512);
    cast_bf16_kernel<<<(2 * S_ * 512 / 4) / 256, 256, 0, stream>>>(Vtab, Vb, 2 * S_ * 512);

    // ---- T iterations ----
    for (int t = 0; t < T_; t++) {
        sync_kernel<<<dim3(B_, 9), 256, 0, stream>>>(act, a_a, dec_act, t, D_MODEL_ - NSY_, s_act);

        init_bias_kernel<<<(B_ * 512 / 4 + 255) / 256, 256, 0, stream>>>(qbuf, 512, bq, B_, 512);
        gemm_bf16<<<dim3(512 / 128, 2, 13), 256, 0, stream>>>(
            s_act, REP_, WqT, REP_, bq, qbuf, 512, B_, 512, REP_, 160);

        // dense attention: scores both tokens via MFMA, then fused softmax+PV
        gemm_qk<<<dim3(S_ / 128, 2, 16), 256, 0, stream>>>(
            qbuf, (const ushort_t*)Kb, scbuf);
        attn_pv<<<B_ * H_, 256, 0, stream>>>(scbuf, Vb, tokens, o_attn);

        init_bias_kernel<<<(B_ * 512 / 4 + 255) / 256, 256, 0, stream>>>(cat, 2560, bo, B_, 512);
        gemm_bf16<<<dim3(512 / 128, 2, 8), 256, 0, stream>>>(
            o_attn, 512, WoT, 512, bo, cat, 2560, B_, 512, 512, 64);

        init_bias_kernel<<<(B_ * 4096 / 4 + 255) / 256, 256, 0, stream>>>(pre, 4096, bs, B_, 4096);
        gemm_bf16<<<dim3(4096 / 128, 2, 8), 256, 0, stream>>>(
            cat, 2560, WsT, 2560, bs, pre, 4096, B_, 4096, 2560, 320);

        glu_ln_kernel<<<B_, 256, 0, stream>>>(pre, ln_s_g, ln_s_b, state);
        trace_kernel<<<(B_ * D_MODEL_) / 256, 256, 0, stream>>>(
            trace, state, ln_n_g, ln_n_b, Wn, bn, temp, act, cat);

        sync_kernel<<<dim3(B_, 9), 256, 0, stream>>>(act, a_o, dec_out, t, 0, s_out);

        init_bias_kernel<<<(B_ * 4096 / 4 + 255) / 256, 256, 0, stream>>>(predb, 4096, bout, B_, 4096);
        gemm_bf16<<<dim3(4096 / 128, 2, 5), 256, 0, stream>>>(
            s_out, REP_, WoutT, REP_, bout, predb, 4096, B_, 4096, REP_, 416);

        out_kernel<<<B_, 256, 0, stream>>>(predb, out, t);
    }
}

// Round 6
// 1521.810 us; speedup vs baseline: 3.9308x; 1.0575x over previous
//
#include <hip/hip_runtime.h>
#include <hip/hip_bf16.h>
#include <math.h>

#define B_ 128
#define S_ 2048
#define D_IN_ 512
#define D_MODEL_ 2048
#define M_ 25
#define NSY_ 64
#define H_ 8
#define T_ 10
#define REP_ 2080
#define DH_ 64
#define PRED_N (B_ * 4096)

typedef unsigned short ushort_t;
typedef __bf16 bf16x8 __attribute__((ext_vector_type(8)));
typedef float f32x4 __attribute__((ext_vector_type(4)));
typedef unsigned short us8 __attribute__((ext_vector_type(8)));

__device__ __forceinline__ ushort_t f2bf(float f) {
    __hip_bfloat16 h = __float2bfloat16(f);
    return *(ushort_t*)&h;
}
__device__ __forceinline__ float bflo(unsigned u) { return __uint_as_float(u << 16); }
__device__ __forceinline__ float bfhi(unsigned u) { return __uint_as_float(u & 0xffff0000u); }

// ---------------------------------------------------------------------------
// MFMA bf16 GEMM, f32 A (cast during staging): C[M,N] (+)= A @ Bt^T
// grid = (N/128, M/64, Z). Z==1: direct store + bias. Z>1: atomicAdd.
// ---------------------------------------------------------------------------
__global__ __launch_bounds__(256) void gemm_bf16(
    const float* __restrict__ A, int lda,
    const ushort_t* __restrict__ Bt, int ldb,
    const float* __restrict__ bias,
    float* __restrict__ C, int ldc,
    int M, int N, int K, int kchunk)
{
    const int nb = blockIdx.x, mb = blockIdx.y, zb = blockIdx.z;
    const int k0 = zb * kchunk;
    const int k1 = min(K, k0 + kchunk);
    __shared__ ushort_t As[64][40];
    __shared__ ushort_t Bs[128][40];

    const int tid  = threadIdx.x;
    const int wave = tid >> 6;
    const int lane = tid & 63;
    const int quad = lane >> 4;
    const int mrow = lane & 15;

    f32x4 acc[4][2];
    #pragma unroll
    for (int s = 0; s < 4; s++)
        #pragma unroll
        for (int u = 0; u < 2; u++)
            acc[s][u] = (f32x4){0.f, 0.f, 0.f, 0.f};

    const int arow = tid >> 2, akc = (tid & 3) * 8;
    const int brow = tid >> 1, bkc = (tid & 1) * 16;

    for (int kk0 = k0; kk0 < k1; kk0 += 32) {
        {
            const float* ap = A + (size_t)(mb * 64 + arow) * lda + kk0 + akc;
            float4 v0 = *(const float4*)ap;
            float4 v1 = *(const float4*)(ap + 4);
            us8 w = { f2bf(v0.x), f2bf(v0.y), f2bf(v0.z), f2bf(v0.w),
                      f2bf(v1.x), f2bf(v1.y), f2bf(v1.z), f2bf(v1.w) };
            *(us8*)&As[arow][akc] = w;
        }
        {
            const ushort_t* bp = Bt + (size_t)(nb * 128 + brow) * ldb + kk0 + bkc;
            *(us8*)&Bs[brow][bkc]     = *(const us8*)bp;
            *(us8*)&Bs[brow][bkc + 8] = *(const us8*)(bp + 8);
        }
        __syncthreads();

        bf16x8 af[4], bfr[2];
        #pragma unroll
        for (int s = 0; s < 4; s++)
            af[s] = *(const bf16x8*)&As[s * 16 + mrow][quad * 8];
        #pragma unroll
        for (int u = 0; u < 2; u++)
            bfr[u] = *(const bf16x8*)&Bs[wave * 32 + u * 16 + mrow][quad * 8];
        #pragma unroll
        for (int s = 0; s < 4; s++)
            #pragma unroll
            for (int u = 0; u < 2; u++)
                acc[s][u] = __builtin_amdgcn_mfma_f32_16x16x32_bf16(
                    af[s], bfr[u], acc[s][u], 0, 0, 0);
        __syncthreads();
    }

    if (gridDim.z == 1) {
        #pragma unroll
        for (int s = 0; s < 4; s++)
            #pragma unroll
            for (int u = 0; u < 2; u++) {
                const int col = nb * 128 + wave * 32 + u * 16 + mrow;
                #pragma unroll
                for (int reg = 0; reg < 4; reg++) {
                    const int row = mb * 64 + s * 16 + quad * 4 + reg;
                    C[(size_t)row * ldc + col] = acc[s][u][reg] + bias[col];
                }
            }
    } else {
        #pragma unroll
        for (int s = 0; s < 4; s++)
            #pragma unroll
            for (int u = 0; u < 2; u++) {
                const int col = nb * 128 + wave * 32 + u * 16 + mrow;
                #pragma unroll
                for (int reg = 0; reg < 4; reg++) {
                    const int row = mb * 64 + s * 16 + quad * 4 + reg;
                    atomicAdd(&C[(size_t)row * ldc + col], acc[s][u][reg]);
                }
            }
    }
}

// ---------------------------------------------------------------------------
// Same GEMM but A is already bf16 (pure-copy staging). Used for q and pred.
// ---------------------------------------------------------------------------
__global__ __launch_bounds__(256) void gemm_bb(
    const ushort_t* __restrict__ A, int lda,
    const ushort_t* __restrict__ Bt, int ldb,
    const float* __restrict__ bias,
    float* __restrict__ C, int ldc,
    int M, int N, int K, int kchunk)
{
    const int nb = blockIdx.x, mb = blockIdx.y, zb = blockIdx.z;
    const int k0 = zb * kchunk;
    const int k1 = min(K, k0 + kchunk);
    __shared__ ushort_t As[64][40];
    __shared__ ushort_t Bs[128][40];

    const int tid  = threadIdx.x;
    const int wave = tid >> 6;
    const int lane = tid & 63;
    const int quad = lane >> 4;
    const int mrow = lane & 15;

    f32x4 acc[4][2];
    #pragma unroll
    for (int s = 0; s < 4; s++)
        #pragma unroll
        for (int u = 0; u < 2; u++)
            acc[s][u] = (f32x4){0.f, 0.f, 0.f, 0.f};

    const int arow = tid >> 2, akc = (tid & 3) * 8;
    const int brow = tid >> 1, bkc = (tid & 1) * 16;

    for (int kk0 = k0; kk0 < k1; kk0 += 32) {
        {
            const ushort_t* ap = A + (size_t)(mb * 64 + arow) * lda + kk0 + akc;
            *(us8*)&As[arow][akc] = *(const us8*)ap;
        }
        {
            const ushort_t* bp = Bt + (size_t)(nb * 128 + brow) * ldb + kk0 + bkc;
            *(us8*)&Bs[brow][bkc]     = *(const us8*)bp;
            *(us8*)&Bs[brow][bkc + 8] = *(const us8*)(bp + 8);
        }
        __syncthreads();

        bf16x8 af[4], bfr[2];
        #pragma unroll
        for (int s = 0; s < 4; s++)
            af[s] = *(const bf16x8*)&As[s * 16 + mrow][quad * 8];
        #pragma unroll
        for (int u = 0; u < 2; u++)
            bfr[u] = *(const bf16x8*)&Bs[wave * 32 + u * 16 + mrow][quad * 8];
        #pragma unroll
        for (int s = 0; s < 4; s++)
            #pragma unroll
            for (int u = 0; u < 2; u++)
                acc[s][u] = __builtin_amdgcn_mfma_f32_16x16x32_bf16(
                    af[s], bfr[u], acc[s][u], 0, 0, 0);
        __syncthreads();
    }

    if (gridDim.z == 1) {
        #pragma unroll
        for (int s = 0; s < 4; s++)
            #pragma unroll
            for (int u = 0; u < 2; u++) {
                const int col = nb * 128 + wave * 32 + u * 16 + mrow;
                #pragma unroll
                for (int reg = 0; reg < 4; reg++) {
                    const int row = mb * 64 + s * 16 + quad * 4 + reg;
                    C[(size_t)row * ldc + col] = acc[s][u][reg] + bias[col];
                }
            }
    } else {
        #pragma unroll
        for (int s = 0; s < 4; s++)
            #pragma unroll
            for (int u = 0; u < 2; u++) {
                const int col = nb * 128 + wave * 32 + u * 16 + mrow;
                #pragma unroll
                for (int reg = 0; reg < 4; reg++) {
                    const int row = mb * 64 + s * 16 + quad * 4 + reg;
                    atomicAdd(&C[(size_t)row * ldc + col], acc[s][u][reg]);
                }
            }
    }
}

// ---------------------------------------------------------------------------
// QK scores, dense both-token: sc[(c*8+h)*128+b][s] = 0.125 * q_bh . K_chs
// grid = (S/128, B/64, 16)
// ---------------------------------------------------------------------------
__global__ __launch_bounds__(256) void gemm_qk(
    const float* __restrict__ q,
    const ushort_t* __restrict__ Kb,
    float* __restrict__ sc)
{
    const int nb = blockIdx.x, mb = blockIdx.y, z = blockIdx.z;
    const int c = z >> 3, h = z & 7;
    __shared__ ushort_t As[64][40];
    __shared__ ushort_t Bs[128][40];

    const int tid  = threadIdx.x;
    const int wave = tid >> 6;
    const int lane = tid & 63;
    const int quad = lane >> 4;
    const int mrow = lane & 15;

    f32x4 acc[4][2];
    #pragma unroll
    for (int s = 0; s < 4; s++)
        #pragma unroll
        for (int u = 0; u < 2; u++)
            acc[s][u] = (f32x4){0.f, 0.f, 0.f, 0.f};

    const int arow = tid >> 2, akc = (tid & 3) * 8;
    const int brow = tid >> 1, bkc = (tid & 1) * 16;
    const float* Abase = q + (size_t)h * 64;
    const ushort_t* Bbase = Kb + (size_t)c * S_ * 512 + h * 64;

    #pragma unroll
    for (int kk0 = 0; kk0 < 64; kk0 += 32) {
        {
            const float* ap = Abase + (size_t)(mb * 64 + arow) * 512 + kk0 + akc;
            float4 v0 = *(const float4*)ap;
            float4 v1 = *(const float4*)(ap + 4);
            us8 w = { f2bf(v0.x), f2bf(v0.y), f2bf(v0.z), f2bf(v0.w),
                      f2bf(v1.x), f2bf(v1.y), f2bf(v1.z), f2bf(v1.w) };
            *(us8*)&As[arow][akc] = w;
        }
        {
            const ushort_t* bp = Bbase + (size_t)(nb * 128 + brow) * 512 + kk0 + bkc;
            *(us8*)&Bs[brow][bkc]     = *(const us8*)bp;
            *(us8*)&Bs[brow][bkc + 8] = *(const us8*)(bp + 8);
        }
        __syncthreads();

        bf16x8 af[4], bfr[2];
        #pragma unroll
        for (int s = 0; s < 4; s++)
            af[s] = *(const bf16x8*)&As[s * 16 + mrow][quad * 8];
        #pragma unroll
        for (int u = 0; u < 2; u++)
            bfr[u] = *(const bf16x8*)&Bs[wave * 32 + u * 16 + mrow][quad * 8];
        #pragma unroll
        for (int s = 0; s < 4; s++)
            #pragma unroll
            for (int u = 0; u < 2; u++)
                acc[s][u] = __builtin_amdgcn_mfma_f32_16x16x32_bf16(
                    af[s], bfr[u], acc[s][u], 0, 0, 0);
        __syncthreads();
    }

    float* Cb = sc + (size_t)z * 128 * S_;
    #pragma unroll
    for (int s = 0; s < 4; s++)
        #pragma unroll
        for (int u = 0; u < 2; u++) {
            const int col = nb * 128 + wave * 32 + u * 16 + mrow;
            #pragma unroll
            for (int reg = 0; reg < 4; reg++) {
                const int row = mb * 64 + s * 16 + quad * 4 + reg;
                Cb[(size_t)row * S_ + col] = 0.125f * acc[s][u][reg];
            }
        }
}

// ---------------------------------------------------------------------------
// Fused token-select + softmax + dense dual-V pass. One block per (b,h).
// Also initializes cat[:, :512] = bo (blocks bh < 256) for the o-proj gemm.
// ---------------------------------------------------------------------------
__global__ __launch_bounds__(256) void attn_pv(
    const float* __restrict__ sc,             // (16,128,2048)
    const __hip_bfloat16* __restrict__ Vb,    // (2,S,512) bf16
    const int*   __restrict__ tokens,         // (B,S)
    float* __restrict__ o,                    // (B,512)
    float* __restrict__ cat,                  // (B,2560)
    const float* __restrict__ bo)
{
    const int bh = blockIdx.x;
    const int b = bh >> 3, h = bh & 7;
    __shared__ float ps[S_][2];
    __shared__ float red[256];
    __shared__ float po[32][68];
    const int tid = threadIdx.x;

    // folded init: cat[:, :512] = bo
    if (bh < 256) {
        const int idx = bh * 256 + tid;      // 0..65535
        const int ib = idx >> 9, in = idx & 511;
        cat[(size_t)ib * 2560 + in] = bo[in];
    }

    const float* sc0 = sc + ((size_t)h * 128 + b) * S_;
    const float* sc1 = sc + ((size_t)(8 + h) * 128 + b) * S_;
    const int* trow = tokens + (size_t)b * S_;

    float lmax = -1e30f;
    int tok[8];
    float sel[8];
    #pragma unroll
    for (int i = 0; i < 8; i++) {
        const int s = tid + i * 256;
        tok[i] = trow[s];
        sel[i] = tok[i] ? sc1[s] : sc0[s];
        lmax = fmaxf(lmax, sel[i]);
    }
    red[tid] = lmax; __syncthreads();
    for (int off = 128; off > 0; off >>= 1) {
        if (tid < off) red[tid] = fmaxf(red[tid], red[tid + off]);
        __syncthreads();
    }
    const float mx = red[0];
    __syncthreads();

    float lsum = 0.f;
    #pragma unroll
    for (int i = 0; i < 8; i++) {
        const int s = tid + i * 256;
        const float e = expf(sel[i] - mx);
        lsum += e;
        ps[s][0] = tok[i] ? 0.f : e;
        ps[s][1] = tok[i] ? e : 0.f;
    }
    red[tid] = lsum; __syncthreads();
    for (int off = 128; off > 0; off >>= 1) {
        if (tid < off) red[tid] += red[tid + off];
        __syncthreads();
    }
    const float inv = 1.f / red[0];

    const int d8 = (tid & 7) * 8;
    const int g  = tid >> 3;
    const __hip_bfloat16* V0 = Vb + (size_t)h * 64 + d8;
    const __hip_bfloat16* V1 = V0 + (size_t)S_ * 512;
    float va[8] = {};
    #pragma unroll 4
    for (int it = 0; it < 64; it++) {
        const int s = g * 64 + ((it + g * 4) & 63);
        const float p0 = ps[s][0];
        const float p1 = ps[s][1];
        uint4 r0 = *(const uint4*)(V0 + (size_t)s * 512);
        uint4 r1 = *(const uint4*)(V1 + (size_t)s * 512);
        va[0] += p0 * bflo(r0.x) + p1 * bflo(r1.x);
        va[1] += p0 * bfhi(r0.x) + p1 * bfhi(r1.x);
        va[2] += p0 * bflo(r0.y) + p1 * bflo(r1.y);
        va[3] += p0 * bfhi(r0.y) + p1 * bfhi(r1.y);
        va[4] += p0 * bflo(r0.z) + p1 * bflo(r1.z);
        va[5] += p0 * bfhi(r0.z) + p1 * bfhi(r1.z);
        va[6] += p0 * bflo(r0.w) + p1 * bflo(r1.w);
        va[7] += p0 * bfhi(r0.w) + p1 * bfhi(r1.w);
    }
    *(float4*)&po[g][d8]     = make_float4(va[0], va[1], va[2], va[3]);
    *(float4*)&po[g][d8 + 4] = make_float4(va[4], va[5], va[6], va[7]);
    __syncthreads();
    if (tid < 64) {
        float acc = 0.f;
        #pragma unroll
        for (int gg = 0; gg < 32; gg++) acc += po[gg][tid];
        o[(size_t)b * 512 + h * 64 + tid] = acc * inv;
    }
}

// ---------------------------------------------------------------------------
__global__ __launch_bounds__(256) void transpose_bf16_kernel(
    const float* __restrict__ in, ushort_t* __restrict__ out, int K, int N)
{
    __shared__ float tile[32][33];
    const int k0 = blockIdx.y * 32, n0 = blockIdx.x * 32;
    const int tx = threadIdx.x & 31, ty4 = (threadIdx.x >> 5) * 4;
    #pragma unroll
    for (int i = 0; i < 4; i++)
        tile[ty4 + i][tx] = in[(size_t)(k0 + ty4 + i) * N + n0 + tx];
    __syncthreads();
    #pragma unroll
    for (int i = 0; i < 4; i++)
        out[(size_t)(n0 + ty4 + i) * K + k0 + tx] = f2bf(tile[tx][ty4 + i]);
}

// ---------------------------------------------------------------------------
__global__ void cast_bf16_kernel(const float* __restrict__ src,
                                 __hip_bfloat16* __restrict__ dst, int n)
{
    const int gid = (blockIdx.x * 256 + threadIdx.x) * 4;
    if (gid >= n) return;
    float4 v = *(const float4*)(src + gid);
    dst[gid + 0] = __float2bfloat16(v.x);
    dst[gid + 1] = __float2bfloat16(v.y);
    dst[gid + 2] = __float2bfloat16(v.z);
    dst[gid + 3] = __float2bfloat16(v.w);
}

// ---------------------------------------------------------------------------
__global__ void feats_kernel(const float* __restrict__ emb,
                             const float* __restrict__ Wp,
                             const float* __restrict__ bp,
                             float* __restrict__ f2)
{
    const int gid = blockIdx.x * 256 + threadIdx.x;
    const int k = gid & 511;
    const int s = (gid >> 9) & (S_ - 1);
    const int c = gid >> 20;
    const float th = 3.14159265358979323846f * (float)s / (float)(S_ - 1);
    f2[gid] = emb[c * 512 + k] + (-sinf(th)) * Wp[k] + cosf(th) * Wp[512 + k] + bp[k];
}

__global__ void init_act_kernel(const float* __restrict__ sa,
                                float* __restrict__ act,
                                float* __restrict__ cat)
{
    const int gid = blockIdx.x * 256 + threadIdx.x;
    const int b = gid >> 11, n = gid & 2047;
    const float v = sa[n];
    act[gid] = v;
    cat[(size_t)b * 2560 + 512 + n] = v;
}

__global__ void init_trace_kernel(const float* __restrict__ st,
                                  float* __restrict__ trace)
{
    const int gid = blockIdx.x * 256 + threadIdx.x;
    trace[gid] = st[gid % (D_MODEL_ * M_)];
}

// ---------------------------------------------------------------------------
// sync: writes bf16 s_out. Block y==8 also initializes up to two bias
// buffers (folded init_bias; runs before the consuming gemm in stream order).
// ---------------------------------------------------------------------------
__global__ void sync_kernel(const float* __restrict__ act,
                            float* __restrict__ alpha,
                            const float* __restrict__ decay,
                            const int t, const int off,
                            ushort_t* __restrict__ sout,
                            float* __restrict__ ib1, const float* __restrict__ bias1, int iN1,
                            float* __restrict__ ib2, const float* __restrict__ bias2, int iN2)
{
    const int b = blockIdx.x;
    const int tid = threadIdx.x;
    if (blockIdx.y == 8) {
        if (ib1)
            for (int n = tid; n < iN1; n += 256)
                ib1[(size_t)b * iN1 + n] = bias1[n];
        if (ib2)
            for (int n = tid; n < iN2; n += 256)
                ib2[(size_t)b * iN2 + n] = bias2[n];
    }
    const int p = blockIdx.y * 256 + tid;
    if (p >= REP_) return;
    int i = 0, rem = p;
    while (rem >= NSY_ - i) { rem -= NSY_ - i; i++; }
    const int j = i + rem;
    const float si = act[(size_t)b * D_MODEL_ + off + i];
    const float sj = act[(size_t)b * D_MODEL_ + off + j];
    const float pair = si * sj;
    const float r = expf(-decay[p]);
    float a;
    if (t == 0) a = pair;
    else        a = r * alpha[(size_t)b * REP_ + p] + pair;
    alpha[(size_t)b * REP_ + p] = a;
    float bta = 1.f;
    for (int k = 0; k < t; k++) bta = r * bta + 1.f;
    sout[(size_t)b * REP_ + p] = f2bf(a / sqrtf(bta));
}

// ---------------------------------------------------------------------------
__global__ __launch_bounds__(256) void glu_ln_kernel(
    const float* __restrict__ pre,
    const float* __restrict__ g,
    const float* __restrict__ bta,
    float* __restrict__ state)
{
    const int b = blockIdx.x;
    const int tid = threadIdx.x;
    __shared__ float v[D_MODEL_];
    __shared__ float r1[256], r2[256];
    float s1 = 0.f, s2 = 0.f;
    #pragma unroll
    for (int i = 0; i < 8; i++) {
        const int dd = tid + i * 256;
        const float g1 = pre[(size_t)b * 4096 + dd];
        const float g2 = pre[(size_t)b * 4096 + 2048 + dd];
        const float val = g1 * (1.f / (1.f + expf(-g2)));
        v[dd] = val; s1 += val; s2 += val * val;
    }
    r1[tid] = s1; r2[tid] = s2; __syncthreads();
    for (int off = 128; off > 0; off >>= 1) {
        if (tid < off) { r1[tid] += r1[tid + off]; r2[tid] += r2[tid + off]; }
        __syncthreads();
    }
    const float mu = r1[0] * (1.f / D_MODEL_);
    const float var = fmaxf(r2[0] * (1.f / D_MODEL_) - mu * mu, 0.f);
    const float inv = 1.f / sqrtf(var + 1e-5f);
    #pragma unroll
    for (int i = 0; i < 8; i++) {
        const int dd = tid + i * 256;
        state[(size_t)b * D_MODEL_ + dd] = (v[dd] - mu) * inv * g[dd] + bta[dd];
    }
}

// ---------------------------------------------------------------------------
__global__ void trace_kernel(float* __restrict__ trace,
                             const float* __restrict__ state,
                             const float* __restrict__ ln_g,
                             const float* __restrict__ ln_b,
                             const float* __restrict__ Wn,
                             const float* __restrict__ bn,
                             const float* __restrict__ temp,
                             float* __restrict__ act,
                             float* __restrict__ cat)
{
    const int gid = blockIdx.x * 256 + threadIdx.x;
    const int b = gid >> 11, n = gid & 2047;
    float* tr = trace + (size_t)gid * M_;
    float x[M_];
    #pragma unroll
    for (int m = 0; m < M_ - 1; m++) x[m] = tr[m + 1];
    x[M_ - 1] = state[gid];
    #pragma unroll
    for (int m = 0; m < M_; m++) tr[m] = x[m];
    float s1 = 0.f, s2 = 0.f;
    #pragma unroll
    for (int m = 0; m < M_; m++) { s1 += x[m]; s2 += x[m] * x[m]; }
    const float mu = s1 * (1.f / M_);
    const float var = fmaxf(s2 * (1.f / M_) - mu * mu, 0.f);
    const float inv = 1.f / sqrtf(var + 1e-5f);
    float y0 = bn[n * 2 + 0], y1 = bn[n * 2 + 1];
    #pragma unroll
    for (int m = 0; m < M_; m++) {
        const float xn = (x[m] - mu) * inv * ln_g[m] + ln_b[m];
        y0 += xn * Wn[(size_t)(m * 2 + 0) * D_MODEL_ + n];
        y1 += xn * Wn[(size_t)(m * 2 + 1) * D_MODEL_ + n];
    }
    const float a = y0 * (1.f / (1.f + expf(-y1))) / temp[0];
    act[gid] = a;
    cat[(size_t)b * 2560 + 512 + n] = a;
}

// ---------------------------------------------------------------------------
// entropy only (preds stay in predstage, contiguous)
// ---------------------------------------------------------------------------
__global__ __launch_bounds__(256) void ent_kernel(
    const float* __restrict__ pred,  // (B,4096) slab of predstage
    float* __restrict__ cert)        // (B,2) slab of certbuf
{
    const int b = blockIdx.x;
    const int tid = threadIdx.x;
    __shared__ float red[256];
    const float* pr = pred + (size_t)b * 4096;
    float sum = 0.f;
    #pragma unroll
    for (int i = 0; i < 8; i++) {
        const int s = tid + i * 256;
        const float l0 = pr[2 * s], l1 = pr[2 * s + 1];
        const float mm = fmaxf(l0, l1);
        const float z0 = expf(l0 - mm), z1 = expf(l1 - mm);
        const float Z = z0 + z1;
        const float lz = logf(Z);
        const float p0 = z0 / Z, p1 = z1 / Z;
        const float lp0 = (l0 - mm) - lz, lp1 = (l1 - mm) - lz;
        sum += -(p0 * lp0 + p1 * lp1) * 1.4426950408889634f;
    }
    red[tid] = sum; __syncthreads();
    for (int off = 128; off > 0; off >>= 1) {
        if (tid < off) red[tid] += red[tid + off];
        __syncthreads();
    }
    if (tid == 0) {
        const float ne = red[0] * (1.f / S_);
        cert[b * 2 + 0] = ne;
        cert[b * 2 + 1] = 1.f - ne;
    }
}

// ---------------------------------------------------------------------------
// final layout: d_out preds (row-major, stride T) from predstage (T, B*4096),
// coalesced via LDS transpose. Block 0 also writes certs.
// grid = PRED_N/1024 = 512 blocks.
// ---------------------------------------------------------------------------
__global__ __launch_bounds__(256) void finalize_kernel(
    const float* __restrict__ predstage,  // (T, B*4096)
    const float* __restrict__ certbuf,    // (T, B*2)
    float* __restrict__ dout)
{
    __shared__ float tile[T_][1024];
    const int tid = threadIdx.x;
    const int row0 = blockIdx.x * 1024;
    #pragma unroll
    for (int t = 0; t < T_; t++) {
        float4 v = *(const float4*)(predstage + (size_t)t * PRED_N + row0 + tid * 4);
        tile[t][tid * 4 + 0] = v.x; tile[t][tid * 4 + 1] = v.y;
        tile[t][tid * 4 + 2] = v.z; tile[t][tid * 4 + 3] = v.w;
    }
    __syncthreads();
    float buf[40];
    #pragma unroll
    for (int r = 0; r < 4; r++)
        #pragma unroll
        for (int t = 0; t < T_; t++)
            buf[r * 10 + t] = tile[t][tid * 4 + r];
    float* dst = dout + (size_t)(row0 + tid * 4) * T_;
    #pragma unroll
    for (int k = 0; k < 10; k++)
        *(float4*)(dst + k * 4) = make_float4(buf[4*k], buf[4*k+1], buf[4*k+2], buf[4*k+3]);

    if (blockIdx.x == 0 && tid < B_) {
        const int b = tid;
        const size_t base = (size_t)PRED_N * T_;
        #pragma unroll
        for (int t = 0; t < T_; t++) {
            dout[base + (size_t)(b * 2 + 0) * T_ + t] = certbuf[t * B_ * 2 + b * 2 + 0];
            dout[base + (size_t)(b * 2 + 1) * T_ + t] = certbuf[t * B_ * 2 + b * 2 + 1];
        }
    }
}

// ---------------------------------------------------------------------------
extern "C" void kernel_launch(void* const* d_in, const int* in_sizes, int n_in,
                              void* d_out, int out_size, void* d_ws, size_t ws_size,
                              hipStream_t stream)
{
    const int*   tokens    = (const int*)  d_in[0];
    const float* emb       = (const float*)d_in[1];
    const float* W_pos     = (const float*)d_in[2];
    const float* b_pos     = (const float*)d_in[3];
    const float* Wq        = (const float*)d_in[4];
    const float* bq        = (const float*)d_in[5];
    const float* Wk        = (const float*)d_in[6];
    const float* bk        = (const float*)d_in[7];
    const float* Wv        = (const float*)d_in[8];
    const float* bv        = (const float*)d_in[9];
    const float* Wo        = (const float*)d_in[10];
    const float* bo        = (const float*)d_in[11];
    const float* Ws        = (const float*)d_in[12];
    const float* bs        = (const float*)d_in[13];
    const float* ln_s_g    = (const float*)d_in[14];
    const float* ln_s_b    = (const float*)d_in[15];
    const float* ln_n_g    = (const float*)d_in[16];
    const float* ln_n_b    = (const float*)d_in[17];
    const float* Wn        = (const float*)d_in[18];
    const float* bn        = (const float*)d_in[19];
    const float* temp      = (const float*)d_in[20];
    const float* Wout      = (const float*)d_in[21];
    const float* bout      = (const float*)d_in[22];
    const float* start_act = (const float*)d_in[23];
    const float* start_tr  = (const float*)d_in[24];
    const float* dec_act   = (const float*)d_in[25];
    const float* dec_out   = (const float*)d_in[26];
    float* out = (float*)d_out;
    float* w = (float*)d_ws;

    // workspace layout (floats)
    size_t off = 0;
    float* f2     = w + off; off += (size_t)2 * S_ * 512;
    float* Ktab   = w + off; off += (size_t)2 * S_ * 512;
    float* Vtab   = w + off; off += (size_t)2 * S_ * 512;
    float* act    = w + off; off += (size_t)B_ * D_MODEL_;
    float* cat    = w + off; off += (size_t)B_ * 2560;
    float* a_a    = w + off; off += (size_t)B_ * REP_;
    float* a_o    = w + off; off += (size_t)B_ * REP_;
    float* qbuf   = w + off; off += (size_t)B_ * 512;
    float* o_attn = w + off; off += (size_t)B_ * 512;
    float* pre    = w + off; off += (size_t)B_ * 4096;
    float* state  = w + off; off += (size_t)B_ * D_MODEL_;
    float* trace  = w + off; off += (size_t)B_ * D_MODEL_ * M_;
    float* scbuf  = w + off; off += (size_t)16 * 128 * S_;
    float* predst = w + off; off += (size_t)T_ * PRED_N;     // (T, B*4096)
    float* certbf = w + off; off += (size_t)T_ * B_ * 2;
    ushort_t* s_actb = (ushort_t*)(w + off); off += (size_t)B_ * REP_ / 2;
    ushort_t* s_outb = (ushort_t*)(w + off); off += (size_t)B_ * REP_ / 2;
    __hip_bfloat16* Kb = (__hip_bfloat16*)(w + off); off += (size_t)S_ * 512;
    __hip_bfloat16* Vb = (__hip_bfloat16*)(w + off); off += (size_t)S_ * 512;
    ushort_t* WkT   = (ushort_t*)(w + off); off += (size_t)512 * 512 / 2;
    ushort_t* WvT   = (ushort_t*)(w + off); off += (size_t)512 * 512 / 2;
    ushort_t* WqT   = (ushort_t*)(w + off); off += (size_t)512 * REP_ / 2;
    ushort_t* WoT   = (ushort_t*)(w + off); off += (size_t)512 * 512 / 2;
    ushort_t* WsT   = (ushort_t*)(w + off); off += (size_t)4096 * 2560 / 2;
    ushort_t* WoutT = (ushort_t*)(w + off); off += (size_t)4096 * REP_ / 2;

    // ---- pre-loop ----
    feats_kernel<<<(2 * S_ * 512) / 256, 256, 0, stream>>>(emb, W_pos, b_pos, f2);
    init_act_kernel<<<(B_ * D_MODEL_) / 256, 256, 0, stream>>>(start_act, act, cat);
    init_trace_kernel<<<(B_ * D_MODEL_ * M_) / 256, 256, 0, stream>>>(start_tr, trace);

    transpose_bf16_kernel<<<dim3(512 / 32, 512 / 32), 256, 0, stream>>>(Wk, WkT, 512, 512);
    transpose_bf16_kernel<<<dim3(512 / 32, 512 / 32), 256, 0, stream>>>(Wv, WvT, 512, 512);
    transpose_bf16_kernel<<<dim3(512 / 32, REP_ / 32), 256, 0, stream>>>(Wq, WqT, REP_, 512);
    transpose_bf16_kernel<<<dim3(512 / 32, 512 / 32), 256, 0, stream>>>(Wo, WoT, 512, 512);
    transpose_bf16_kernel<<<dim3(4096 / 32, 2560 / 32), 256, 0, stream>>>(Ws, WsT, 2560, 4096);
    transpose_bf16_kernel<<<dim3(4096 / 32, REP_ / 32), 256, 0, stream>>>(Wout, WoutT, REP_, 4096);

    gemm_bf16<<<dim3(512 / 128, (2 * S_) / 64, 1), 256, 0, stream>>>(
        f2, 512, WkT, 512, bk, Ktab, 512, 2 * S_, 512, 512, 512);
    gemm_bf16<<<dim3(512 / 128, (2 * S_) / 64, 1), 256, 0, stream>>>(
        f2, 512, WvT, 512, bv, Vtab, 512, 2 * S_, 512, 512, 512);
    cast_bf16_kernel<<<(2 * S_ * 512 / 4) / 256, 256, 0, stream>>>(Ktab, Kb, 2 * S_ * 512);
    cast_bf16_kernel<<<(2 * S_ * 512 / 4) / 256, 256, 0, stream>>>(Vtab, Vb, 2 * S_ * 512);

    // ---- T iterations ----
    for (int t = 0; t < T_; t++) {
        // sync action; y==8 block also inits qbuf=bq and pre=bs
        sync_kernel<<<dim3(B_, 9), 256, 0, stream>>>(
            act, a_a, dec_act, t, D_MODEL_ - NSY_, s_actb,
            qbuf, bq, 512, pre, bs, 4096);

        gemm_bb<<<dim3(512 / 128, 2, 13), 256, 0, stream>>>(
            s_actb, REP_, WqT, REP_, bq, qbuf, 512, B_, 512, REP_, 160);

        gemm_qk<<<dim3(S_ / 128, 2, 16), 256, 0, stream>>>(
            qbuf, (const ushort_t*)Kb, scbuf);
        attn_pv<<<B_ * H_, 256, 0, stream>>>(scbuf, Vb, tokens, o_attn, cat, bo);

        gemm_bf16<<<dim3(512 / 128, 2, 8), 256, 0, stream>>>(
            o_attn, 512, WoT, 512, bo, cat, 2560, B_, 512, 512, 64);

        gemm_bf16<<<dim3(4096 / 128, 2, 8), 256, 0, stream>>>(
            cat, 2560, WsT, 2560, bs, pre, 4096, B_, 4096, 2560, 320);

        glu_ln_kernel<<<B_, 256, 0, stream>>>(pre, ln_s_g, ln_s_b, state);
        trace_kernel<<<(B_ * D_MODEL_) / 256, 256, 0, stream>>>(
            trace, state, ln_n_g, ln_n_b, Wn, bn, temp, act, cat);

        // sync out; y==8 block inits predstage_t = bout
        float* predt = predst + (size_t)t * PRED_N;
        sync_kernel<<<dim3(B_, 9), 256, 0, stream>>>(
            act, a_o, dec_out, t, 0, s_outb,
            predt, bout, 4096, nullptr, nullptr, 0);

        gemm_bb<<<dim3(4096 / 128, 2, 5), 256, 0, stream>>>(
            s_outb, REP_, WoutT, REP_, bout, predt, 4096, B_, 4096, REP_, 416);

        ent_kernel<<<B_, 256, 0, stream>>>(predt, certbf + t * B_ * 2);
    }

    // one coalesced pass to the strided output layout
    finalize_kernel<<<PRED_N / 1024, 256, 0, stream>>>(predst, certbf, out);
}

// Round 7
// 1492.372 us; speedup vs baseline: 4.0083x; 1.0197x over previous
//
#include <hip/hip_runtime.h>
#include <hip/hip_bf16.h>
#include <math.h>

#define B_ 128
#define S_ 2048
#define D_IN_ 512
#define D_MODEL_ 2048
#define M_ 25
#define NSY_ 64
#define H_ 8
#define T_ 10
#define REP_ 2080
#define DH_ 64
#define PRED_N (B_ * 4096)

typedef unsigned short ushort_t;
typedef __bf16 bf16x8 __attribute__((ext_vector_type(8)));
typedef float f32x4 __attribute__((ext_vector_type(4)));
typedef unsigned short us8 __attribute__((ext_vector_type(8)));

__device__ __forceinline__ ushort_t f2bf(float f) {
    __hip_bfloat16 h = __float2bfloat16(f);
    return *(ushort_t*)&h;
}
__device__ __forceinline__ float bflo(unsigned u) { return __uint_as_float(u << 16); }
__device__ __forceinline__ float bfhi(unsigned u) { return __uint_as_float(u & 0xffff0000u); }

// ---------------------------------------------------------------------------
// MFMA bf16 GEMM, f32 A (cast during staging): C[M,N] (+)= A @ Bt^T
// grid = (N/128, M/64, Z). Z==1: direct store + bias. Z>1: atomicAdd.
// ---------------------------------------------------------------------------
__global__ __launch_bounds__(256) void gemm_bf16(
    const float* __restrict__ A, int lda,
    const ushort_t* __restrict__ Bt, int ldb,
    const float* __restrict__ bias,
    float* __restrict__ C, int ldc,
    int M, int N, int K, int kchunk)
{
    const int nb = blockIdx.x, mb = blockIdx.y, zb = blockIdx.z;
    const int k0 = zb * kchunk;
    const int k1 = min(K, k0 + kchunk);
    __shared__ ushort_t As[64][40];
    __shared__ ushort_t Bs[128][40];

    const int tid  = threadIdx.x;
    const int wave = tid >> 6;
    const int lane = tid & 63;
    const int quad = lane >> 4;
    const int mrow = lane & 15;

    f32x4 acc[4][2];
    #pragma unroll
    for (int s = 0; s < 4; s++)
        #pragma unroll
        for (int u = 0; u < 2; u++)
            acc[s][u] = (f32x4){0.f, 0.f, 0.f, 0.f};

    const int arow = tid >> 2, akc = (tid & 3) * 8;
    const int brow = tid >> 1, bkc = (tid & 1) * 16;

    for (int kk0 = k0; kk0 < k1; kk0 += 32) {
        {
            const float* ap = A + (size_t)(mb * 64 + arow) * lda + kk0 + akc;
            float4 v0 = *(const float4*)ap;
            float4 v1 = *(const float4*)(ap + 4);
            us8 w = { f2bf(v0.x), f2bf(v0.y), f2bf(v0.z), f2bf(v0.w),
                      f2bf(v1.x), f2bf(v1.y), f2bf(v1.z), f2bf(v1.w) };
            *(us8*)&As[arow][akc] = w;
        }
        {
            const ushort_t* bp = Bt + (size_t)(nb * 128 + brow) * ldb + kk0 + bkc;
            *(us8*)&Bs[brow][bkc]     = *(const us8*)bp;
            *(us8*)&Bs[brow][bkc + 8] = *(const us8*)(bp + 8);
        }
        __syncthreads();

        bf16x8 af[4], bfr[2];
        #pragma unroll
        for (int s = 0; s < 4; s++)
            af[s] = *(const bf16x8*)&As[s * 16 + mrow][quad * 8];
        #pragma unroll
        for (int u = 0; u < 2; u++)
            bfr[u] = *(const bf16x8*)&Bs[wave * 32 + u * 16 + mrow][quad * 8];
        #pragma unroll
        for (int s = 0; s < 4; s++)
            #pragma unroll
            for (int u = 0; u < 2; u++)
                acc[s][u] = __builtin_amdgcn_mfma_f32_16x16x32_bf16(
                    af[s], bfr[u], acc[s][u], 0, 0, 0);
        __syncthreads();
    }

    if (gridDim.z == 1) {
        #pragma unroll
        for (int s = 0; s < 4; s++)
            #pragma unroll
            for (int u = 0; u < 2; u++) {
                const int col = nb * 128 + wave * 32 + u * 16 + mrow;
                #pragma unroll
                for (int reg = 0; reg < 4; reg++) {
                    const int row = mb * 64 + s * 16 + quad * 4 + reg;
                    C[(size_t)row * ldc + col] = acc[s][u][reg] + bias[col];
                }
            }
    } else {
        #pragma unroll
        for (int s = 0; s < 4; s++)
            #pragma unroll
            for (int u = 0; u < 2; u++) {
                const int col = nb * 128 + wave * 32 + u * 16 + mrow;
                #pragma unroll
                for (int reg = 0; reg < 4; reg++) {
                    const int row = mb * 64 + s * 16 + quad * 4 + reg;
                    atomicAdd(&C[(size_t)row * ldc + col], acc[s][u][reg]);
                }
            }
    }
}

// ---------------------------------------------------------------------------
// Same GEMM but A already bf16 (pure-copy staging). Used for q and pred.
// ---------------------------------------------------------------------------
__global__ __launch_bounds__(256) void gemm_bb(
    const ushort_t* __restrict__ A, int lda,
    const ushort_t* __restrict__ Bt, int ldb,
    const float* __restrict__ bias,
    float* __restrict__ C, int ldc,
    int M, int N, int K, int kchunk)
{
    const int nb = blockIdx.x, mb = blockIdx.y, zb = blockIdx.z;
    const int k0 = zb * kchunk;
    const int k1 = min(K, k0 + kchunk);
    __shared__ ushort_t As[64][40];
    __shared__ ushort_t Bs[128][40];

    const int tid  = threadIdx.x;
    const int wave = tid >> 6;
    const int lane = tid & 63;
    const int quad = lane >> 4;
    const int mrow = lane & 15;

    f32x4 acc[4][2];
    #pragma unroll
    for (int s = 0; s < 4; s++)
        #pragma unroll
        for (int u = 0; u < 2; u++)
            acc[s][u] = (f32x4){0.f, 0.f, 0.f, 0.f};

    const int arow = tid >> 2, akc = (tid & 3) * 8;
    const int brow = tid >> 1, bkc = (tid & 1) * 16;

    for (int kk0 = k0; kk0 < k1; kk0 += 32) {
        {
            const ushort_t* ap = A + (size_t)(mb * 64 + arow) * lda + kk0 + akc;
            *(us8*)&As[arow][akc] = *(const us8*)ap;
        }
        {
            const ushort_t* bp = Bt + (size_t)(nb * 128 + brow) * ldb + kk0 + bkc;
            *(us8*)&Bs[brow][bkc]     = *(const us8*)bp;
            *(us8*)&Bs[brow][bkc + 8] = *(const us8*)(bp + 8);
        }
        __syncthreads();

        bf16x8 af[4], bfr[2];
        #pragma unroll
        for (int s = 0; s < 4; s++)
            af[s] = *(const bf16x8*)&As[s * 16 + mrow][quad * 8];
        #pragma unroll
        for (int u = 0; u < 2; u++)
            bfr[u] = *(const bf16x8*)&Bs[wave * 32 + u * 16 + mrow][quad * 8];
        #pragma unroll
        for (int s = 0; s < 4; s++)
            #pragma unroll
            for (int u = 0; u < 2; u++)
                acc[s][u] = __builtin_amdgcn_mfma_f32_16x16x32_bf16(
                    af[s], bfr[u], acc[s][u], 0, 0, 0);
        __syncthreads();
    }

    if (gridDim.z == 1) {
        #pragma unroll
        for (int s = 0; s < 4; s++)
            #pragma unroll
            for (int u = 0; u < 2; u++) {
                const int col = nb * 128 + wave * 32 + u * 16 + mrow;
                #pragma unroll
                for (int reg = 0; reg < 4; reg++) {
                    const int row = mb * 64 + s * 16 + quad * 4 + reg;
                    C[(size_t)row * ldc + col] = acc[s][u][reg] + bias[col];
                }
            }
    } else {
        #pragma unroll
        for (int s = 0; s < 4; s++)
            #pragma unroll
            for (int u = 0; u < 2; u++) {
                const int col = nb * 128 + wave * 32 + u * 16 + mrow;
                #pragma unroll
                for (int reg = 0; reg < 4; reg++) {
                    const int row = mb * 64 + s * 16 + quad * 4 + reg;
                    atomicAdd(&C[(size_t)row * ldc + col], acc[s][u][reg]);
                }
            }
    }
}

// ---------------------------------------------------------------------------
// QK scores, dense both-token: sc[(c*8+h)*128+b][s] = 0.125 * q_bh . K_chs
// grid = (S/128, B/64, 16)
// ---------------------------------------------------------------------------
__global__ __launch_bounds__(256) void gemm_qk(
    const float* __restrict__ q,
    const ushort_t* __restrict__ Kb,
    float* __restrict__ sc)
{
    const int nb = blockIdx.x, mb = blockIdx.y, z = blockIdx.z;
    const int c = z >> 3, h = z & 7;
    __shared__ ushort_t As[64][40];
    __shared__ ushort_t Bs[128][40];

    const int tid  = threadIdx.x;
    const int wave = tid >> 6;
    const int lane = tid & 63;
    const int quad = lane >> 4;
    const int mrow = lane & 15;

    f32x4 acc[4][2];
    #pragma unroll
    for (int s = 0; s < 4; s++)
        #pragma unroll
        for (int u = 0; u < 2; u++)
            acc[s][u] = (f32x4){0.f, 0.f, 0.f, 0.f};

    const int arow = tid >> 2, akc = (tid & 3) * 8;
    const int brow = tid >> 1, bkc = (tid & 1) * 16;
    const float* Abase = q + (size_t)h * 64;
    const ushort_t* Bbase = Kb + (size_t)c * S_ * 512 + h * 64;

    #pragma unroll
    for (int kk0 = 0; kk0 < 64; kk0 += 32) {
        {
            const float* ap = Abase + (size_t)(mb * 64 + arow) * 512 + kk0 + akc;
            float4 v0 = *(const float4*)ap;
            float4 v1 = *(const float4*)(ap + 4);
            us8 w = { f2bf(v0.x), f2bf(v0.y), f2bf(v0.z), f2bf(v0.w),
                      f2bf(v1.x), f2bf(v1.y), f2bf(v1.z), f2bf(v1.w) };
            *(us8*)&As[arow][akc] = w;
        }
        {
            const ushort_t* bp = Bbase + (size_t)(nb * 128 + brow) * 512 + kk0 + bkc;
            *(us8*)&Bs[brow][bkc]     = *(const us8*)bp;
            *(us8*)&Bs[brow][bkc + 8] = *(const us8*)(bp + 8);
        }
        __syncthreads();

        bf16x8 af[4], bfr[2];
        #pragma unroll
        for (int s = 0; s < 4; s++)
            af[s] = *(const bf16x8*)&As[s * 16 + mrow][quad * 8];
        #pragma unroll
        for (int u = 0; u < 2; u++)
            bfr[u] = *(const bf16x8*)&Bs[wave * 32 + u * 16 + mrow][quad * 8];
        #pragma unroll
        for (int s = 0; s < 4; s++)
            #pragma unroll
            for (int u = 0; u < 2; u++)
                acc[s][u] = __builtin_amdgcn_mfma_f32_16x16x32_bf16(
                    af[s], bfr[u], acc[s][u], 0, 0, 0);
        __syncthreads();
    }

    float* Cb = sc + (size_t)z * 128 * S_;
    #pragma unroll
    for (int s = 0; s < 4; s++)
        #pragma unroll
        for (int u = 0; u < 2; u++) {
            const int col = nb * 128 + wave * 32 + u * 16 + mrow;
            #pragma unroll
            for (int reg = 0; reg < 4; reg++) {
                const int row = mb * 64 + s * 16 + quad * 4 + reg;
                Cb[(size_t)row * S_ + col] = 0.125f * acc[s][u][reg];
            }
        }
}

// ---------------------------------------------------------------------------
// token-select + softmax -> normalized P (bf16, packed per-s pair).
// P[h][b][s*2+c]. Also: cat[:, :512]=bo (bh<256), o_attn=0 (bh in [256,320)).
// ---------------------------------------------------------------------------
__global__ __launch_bounds__(256) void attn_soft(
    const float* __restrict__ sc,             // (16,128,2048)
    const int*   __restrict__ tokens,         // (B,S)
    ushort_t* __restrict__ P,                 // (8,128,4096)
    float* __restrict__ o,                    // (B,512) -> zeroed
    float* __restrict__ cat,                  // (B,2560)
    const float* __restrict__ bo)
{
    const int bh = blockIdx.x;
    const int b = bh >> 3, h = bh & 7;
    __shared__ float red[256];
    const int tid = threadIdx.x;

    if (bh < 256) {
        const int idx = bh * 256 + tid;
        cat[(size_t)(idx >> 9) * 2560 + (idx & 511)] = bo[idx & 511];
    } else if (bh < 320) {
        const int idx = (bh - 256) * 256 + tid;   // 0..16383
        *(float4*)&o[idx * 4] = make_float4(0.f, 0.f, 0.f, 0.f);
    }

    const float* sc0 = sc + ((size_t)h * 128 + b) * S_;
    const float* sc1 = sc + ((size_t)(8 + h) * 128 + b) * S_;
    const int* trow = tokens + (size_t)b * S_;

    int tok[8]; float sel[8];
    float lmax = -1e30f;
    #pragma unroll
    for (int i = 0; i < 8; i++) {
        const int s = tid + i * 256;
        tok[i] = trow[s];
        sel[i] = tok[i] ? sc1[s] : sc0[s];
        lmax = fmaxf(lmax, sel[i]);
    }
    red[tid] = lmax; __syncthreads();
    for (int off = 128; off > 0; off >>= 1) {
        if (tid < off) red[tid] = fmaxf(red[tid], red[tid + off]);
        __syncthreads();
    }
    const float mx = red[0];
    __syncthreads();

    float e[8];
    float lsum = 0.f;
    #pragma unroll
    for (int i = 0; i < 8; i++) {
        e[i] = expf(sel[i] - mx);
        lsum += e[i];
    }
    red[tid] = lsum; __syncthreads();
    for (int off = 128; off > 0; off >>= 1) {
        if (tid < off) red[tid] += red[tid + off];
        __syncthreads();
    }
    const float inv = 1.f / red[0];

    ushort_t* Pb = P + ((size_t)h * 128 + b) * 4096;
    #pragma unroll
    for (int i = 0; i < 8; i++) {
        const int s = tid + i * 256;
        const unsigned p = (unsigned)f2bf(e[i] * inv);
        const unsigned word = tok[i] ? (p << 16) : p;
        *(unsigned*)&Pb[s * 2] = word;
    }
}

// ---------------------------------------------------------------------------
// PV via MFMA: o[b, h*64+d] += sum_k P[h][b][k] * VT[h][d][k], k=s*2+c (4096)
// grid = (2 mb, 8 h, 8 z). kchunk=512. atomicAdd into pre-zeroed o.
// ---------------------------------------------------------------------------
__global__ __launch_bounds__(256) void gemm_pv(
    const ushort_t* __restrict__ P,    // (8,128,4096)
    const ushort_t* __restrict__ VT,   // (8,64,4096)
    float* __restrict__ o)             // (128,512)
{
    const int mb = blockIdx.x, h = blockIdx.y, zb = blockIdx.z;
    const int k0 = zb * 512;
    __shared__ ushort_t As[64][40];
    __shared__ ushort_t Bs[64][40];

    const int tid  = threadIdx.x;
    const int wave = tid >> 6;
    const int lane = tid & 63;
    const int quad = lane >> 4;
    const int mrow = lane & 15;

    f32x4 acc[4];
    #pragma unroll
    for (int s = 0; s < 4; s++) acc[s] = (f32x4){0.f, 0.f, 0.f, 0.f};

    const int row = tid >> 2, kc = (tid & 3) * 8;
    const ushort_t* Ab = P  + ((size_t)h * 128 + mb * 64 + row) * 4096;
    const ushort_t* Bb = VT + ((size_t)h * 64 + row) * 4096;

    for (int kk = k0; kk < k0 + 512; kk += 32) {
        *(us8*)&As[row][kc] = *(const us8*)(Ab + kk + kc);
        *(us8*)&Bs[row][kc] = *(const us8*)(Bb + kk + kc);
        __syncthreads();
        bf16x8 bfr = *(const bf16x8*)&Bs[wave * 16 + mrow][quad * 8];
        #pragma unroll
        for (int s = 0; s < 4; s++) {
            bf16x8 af = *(const bf16x8*)&As[s * 16 + mrow][quad * 8];
            acc[s] = __builtin_amdgcn_mfma_f32_16x16x32_bf16(af, bfr, acc[s], 0, 0, 0);
        }
        __syncthreads();
    }

    const int col = h * 64 + wave * 16 + mrow;
    #pragma unroll
    for (int s = 0; s < 4; s++)
        #pragma unroll
        for (int reg = 0; reg < 4; reg++) {
            const int rowi = mb * 64 + s * 16 + quad * 4 + reg;
            atomicAdd(&o[(size_t)rowi * 512 + col], acc[s][reg]);
        }
}

// ---------------------------------------------------------------------------
// VT[h][d][s*2+c] = bf16(Vtab[(c*S+s)*512 + h*64+d])   (one-time)
// ---------------------------------------------------------------------------
__global__ void build_vt(const float* __restrict__ Vtab, ushort_t* __restrict__ VT)
{
    const int gid = blockIdx.x * 256 + threadIdx.x;  // 8*64*4096
    const int k = gid & 4095;
    const int d = (gid >> 12) & 63;
    const int h = gid >> 18;
    const int s = k >> 1, c = k & 1;
    VT[gid] = f2bf(Vtab[((size_t)(c * S_ + s)) * 512 + h * 64 + d]);
}

// ---------------------------------------------------------------------------
__global__ __launch_bounds__(256) void transpose_bf16_kernel(
    const float* __restrict__ in, ushort_t* __restrict__ out, int K, int N)
{
    __shared__ float tile[32][33];
    const int k0 = blockIdx.y * 32, n0 = blockIdx.x * 32;
    const int tx = threadIdx.x & 31, ty4 = (threadIdx.x >> 5) * 4;
    #pragma unroll
    for (int i = 0; i < 4; i++)
        tile[ty4 + i][tx] = in[(size_t)(k0 + ty4 + i) * N + n0 + tx];
    __syncthreads();
    #pragma unroll
    for (int i = 0; i < 4; i++)
        out[(size_t)(n0 + ty4 + i) * K + k0 + tx] = f2bf(tile[tx][ty4 + i]);
}

// ---------------------------------------------------------------------------
__global__ void cast_bf16_kernel(const float* __restrict__ src,
                                 __hip_bfloat16* __restrict__ dst, int n)
{
    const int gid = (blockIdx.x * 256 + threadIdx.x) * 4;
    if (gid >= n) return;
    float4 v = *(const float4*)(src + gid);
    dst[gid + 0] = __float2bfloat16(v.x);
    dst[gid + 1] = __float2bfloat16(v.y);
    dst[gid + 2] = __float2bfloat16(v.z);
    dst[gid + 3] = __float2bfloat16(v.w);
}

// ---------------------------------------------------------------------------
__global__ void feats_kernel(const float* __restrict__ emb,
                             const float* __restrict__ Wp,
                             const float* __restrict__ bp,
                             float* __restrict__ f2)
{
    const int gid = blockIdx.x * 256 + threadIdx.x;
    const int k = gid & 511;
    const int s = (gid >> 9) & (S_ - 1);
    const int c = gid >> 20;
    const float th = 3.14159265358979323846f * (float)s / (float)(S_ - 1);
    f2[gid] = emb[c * 512 + k] + (-sinf(th)) * Wp[k] + cosf(th) * Wp[512 + k] + bp[k];
}

__global__ void init_act_kernel(const float* __restrict__ sa,
                                float* __restrict__ act,
                                float* __restrict__ cat)
{
    const int gid = blockIdx.x * 256 + threadIdx.x;
    const int b = gid >> 11, n = gid & 2047;
    const float v = sa[n];
    act[gid] = v;
    cat[(size_t)b * 2560 + 512 + n] = v;
}

__global__ void init_trace_kernel(const float* __restrict__ st,
                                  float* __restrict__ trace)
{
    const int gid = blockIdx.x * 256 + threadIdx.x;
    trace[gid] = st[gid % (D_MODEL_ * M_)];
}

// ---------------------------------------------------------------------------
// sync: writes bf16 s_out. Block y==8 also initializes up to two bias
// buffers (folded init_bias).
// ---------------------------------------------------------------------------
__global__ void sync_kernel(const float* __restrict__ act,
                            float* __restrict__ alpha,
                            const float* __restrict__ decay,
                            const int t, const int off,
                            ushort_t* __restrict__ sout,
                            float* __restrict__ ib1, const float* __restrict__ bias1, int iN1,
                            float* __restrict__ ib2, const float* __restrict__ bias2, int iN2)
{
    const int b = blockIdx.x;
    const int tid = threadIdx.x;
    if (blockIdx.y == 8) {
        if (ib1)
            for (int n = tid; n < iN1; n += 256)
                ib1[(size_t)b * iN1 + n] = bias1[n];
        if (ib2)
            for (int n = tid; n < iN2; n += 256)
                ib2[(size_t)b * iN2 + n] = bias2[n];
    }
    const int p = blockIdx.y * 256 + tid;
    if (p >= REP_) return;
    int i = 0, rem = p;
    while (rem >= NSY_ - i) { rem -= NSY_ - i; i++; }
    const int j = i + rem;
    const float si = act[(size_t)b * D_MODEL_ + off + i];
    const float sj = act[(size_t)b * D_MODEL_ + off + j];
    const float pair = si * sj;
    const float r = expf(-decay[p]);
    float a;
    if (t == 0) a = pair;
    else        a = r * alpha[(size_t)b * REP_ + p] + pair;
    alpha[(size_t)b * REP_ + p] = a;
    float bta = 1.f;
    for (int k = 0; k < t; k++) bta = r * bta + 1.f;
    sout[(size_t)b * REP_ + p] = f2bf(a / sqrtf(bta));
}

// ---------------------------------------------------------------------------
// fused: state = LN(glu(pre)); trace shift+LN+Wn proj -> act, cat.
// grid = 256 blocks: (b, half). LN recomputed per half (cheap, keeps BW).
// ---------------------------------------------------------------------------
__global__ __launch_bounds__(256) void state_trace_kernel(
    const float* __restrict__ pre,    // (B,4096)
    const float* __restrict__ g,
    const float* __restrict__ bt,
    float* __restrict__ trace,        // (B,2048,25)
    const float* __restrict__ ln_g,   // (25)
    const float* __restrict__ ln_b,   // (25)
    const float* __restrict__ Wn,     // (25,2,2048)
    const float* __restrict__ bn,     // (2048,2)
    const float* __restrict__ temp,   // (1)
    float* __restrict__ act,          // (B,2048)
    float* __restrict__ cat)          // (B,2560)
{
    const int b = blockIdx.x >> 1, half = blockIdx.x & 1;
    const int tid = threadIdx.x;
    __shared__ float v[D_MODEL_];
    __shared__ float r1[256], r2[256];
    float s1 = 0.f, s2 = 0.f;
    #pragma unroll
    for (int i = 0; i < 8; i++) {
        const int dd = tid + i * 256;
        const float g1 = pre[(size_t)b * 4096 + dd];
        const float g2 = pre[(size_t)b * 4096 + 2048 + dd];
        const float val = g1 * (1.f / (1.f + expf(-g2)));
        v[dd] = val; s1 += val; s2 += val * val;
    }
    r1[tid] = s1; r2[tid] = s2; __syncthreads();
    for (int off = 128; off > 0; off >>= 1) {
        if (tid < off) { r1[tid] += r1[tid + off]; r2[tid] += r2[tid + off]; }
        __syncthreads();
    }
    const float mu = r1[0] * (1.f / D_MODEL_);
    const float var = fmaxf(r2[0] * (1.f / D_MODEL_) - mu * mu, 0.f);
    const float sinv = 1.f / sqrtf(var + 1e-5f);
    const float tval = temp[0];

    #pragma unroll
    for (int i = 0; i < 4; i++) {
        const int n = half * 1024 + i * 256 + tid;
        const float sval = (v[n] - mu) * sinv * g[n] + bt[n];
        const int gid = b * 2048 + n;
        float* tr = trace + (size_t)gid * M_;
        float x[M_];
        #pragma unroll
        for (int m = 0; m < M_ - 1; m++) x[m] = tr[m + 1];
        x[M_ - 1] = sval;
        #pragma unroll
        for (int m = 0; m < M_; m++) tr[m] = x[m];
        float t1 = 0.f, t2 = 0.f;
        #pragma unroll
        for (int m = 0; m < M_; m++) { t1 += x[m]; t2 += x[m] * x[m]; }
        const float tmu = t1 * (1.f / M_);
        const float tvar = fmaxf(t2 * (1.f / M_) - tmu * tmu, 0.f);
        const float tinv = 1.f / sqrtf(tvar + 1e-5f);
        float y0 = bn[n * 2 + 0], y1 = bn[n * 2 + 1];
        #pragma unroll
        for (int m = 0; m < M_; m++) {
            const float xn = (x[m] - tmu) * tinv * ln_g[m] + ln_b[m];
            y0 += xn * Wn[(size_t)(m * 2 + 0) * D_MODEL_ + n];
            y1 += xn * Wn[(size_t)(m * 2 + 1) * D_MODEL_ + n];
        }
        const float a = y0 * (1.f / (1.f + expf(-y1))) / tval;
        act[gid] = a;
        cat[(size_t)b * 2560 + 512 + n] = a;
    }
}

// ---------------------------------------------------------------------------
__global__ __launch_bounds__(256) void ent_kernel(
    const float* __restrict__ pred,  // (B,4096) slab of predstage
    float* __restrict__ cert)        // (B,2) slab of certbuf
{
    const int b = blockIdx.x;
    const int tid = threadIdx.x;
    __shared__ float red[256];
    const float* pr = pred + (size_t)b * 4096;
    float sum = 0.f;
    #pragma unroll
    for (int i = 0; i < 8; i++) {
        const int s = tid + i * 256;
        const float l0 = pr[2 * s], l1 = pr[2 * s + 1];
        const float mm = fmaxf(l0, l1);
        const float z0 = expf(l0 - mm), z1 = expf(l1 - mm);
        const float Z = z0 + z1;
        const float lz = logf(Z);
        const float p0 = z0 / Z, p1 = z1 / Z;
        const float lp0 = (l0 - mm) - lz, lp1 = (l1 - mm) - lz;
        sum += -(p0 * lp0 + p1 * lp1) * 1.4426950408889634f;
    }
    red[tid] = sum; __syncthreads();
    for (int off = 128; off > 0; off >>= 1) {
        if (tid < off) red[tid] += red[tid + off];
        __syncthreads();
    }
    if (tid == 0) {
        const float ne = red[0] * (1.f / S_);
        cert[b * 2 + 0] = ne;
        cert[b * 2 + 1] = 1.f - ne;
    }
}

// ---------------------------------------------------------------------------
__global__ __launch_bounds__(256) void finalize_kernel(
    const float* __restrict__ predstage,  // (T, B*4096)
    const float* __restrict__ certbuf,    // (T, B*2)
    float* __restrict__ dout)
{
    __shared__ float tile[T_][1024];
    const int tid = threadIdx.x;
    const int row0 = blockIdx.x * 1024;
    #pragma unroll
    for (int t = 0; t < T_; t++) {
        float4 v = *(const float4*)(predstage + (size_t)t * PRED_N + row0 + tid * 4);
        tile[t][tid * 4 + 0] = v.x; tile[t][tid * 4 + 1] = v.y;
        tile[t][tid * 4 + 2] = v.z; tile[t][tid * 4 + 3] = v.w;
    }
    __syncthreads();
    float buf[40];
    #pragma unroll
    for (int r = 0; r < 4; r++)
        #pragma unroll
        for (int t = 0; t < T_; t++)
            buf[r * 10 + t] = tile[t][tid * 4 + r];
    float* dst = dout + (size_t)(row0 + tid * 4) * T_;
    #pragma unroll
    for (int k = 0; k < 10; k++)
        *(float4*)(dst + k * 4) = make_float4(buf[4*k], buf[4*k+1], buf[4*k+2], buf[4*k+3]);

    if (blockIdx.x == 0 && tid < B_) {
        const int b = tid;
        const size_t base = (size_t)PRED_N * T_;
        #pragma unroll
        for (int t = 0; t < T_; t++) {
            dout[base + (size_t)(b * 2 + 0) * T_ + t] = certbuf[t * B_ * 2 + b * 2 + 0];
            dout[base + (size_t)(b * 2 + 1) * T_ + t] = certbuf[t * B_ * 2 + b * 2 + 1];
        }
    }
}

// ---------------------------------------------------------------------------
extern "C" void kernel_launch(void* const* d_in, const int* in_sizes, int n_in,
                              void* d_out, int out_size, void* d_ws, size_t ws_size,
                              hipStream_t stream)
{
    const int*   tokens    = (const int*)  d_in[0];
    const float* emb       = (const float*)d_in[1];
    const float* W_pos     = (const float*)d_in[2];
    const float* b_pos     = (const float*)d_in[3];
    const float* Wq        = (const float*)d_in[4];
    const float* bq        = (const float*)d_in[5];
    const float* Wk        = (const float*)d_in[6];
    const float* bk        = (const float*)d_in[7];
    const float* Wv        = (const float*)d_in[8];
    const float* bv        = (const float*)d_in[9];
    const float* Wo        = (const float*)d_in[10];
    const float* bo        = (const float*)d_in[11];
    const float* Ws        = (const float*)d_in[12];
    const float* bs        = (const float*)d_in[13];
    const float* ln_s_g    = (const float*)d_in[14];
    const float* ln_s_b    = (const float*)d_in[15];
    const float* ln_n_g    = (const float*)d_in[16];
    const float* ln_n_b    = (const float*)d_in[17];
    const float* Wn        = (const float*)d_in[18];
    const float* bn        = (const float*)d_in[19];
    const float* temp      = (const float*)d_in[20];
    const float* Wout      = (const float*)d_in[21];
    const float* bout      = (const float*)d_in[22];
    const float* start_act = (const float*)d_in[23];
    const float* start_tr  = (const float*)d_in[24];
    const float* dec_act   = (const float*)d_in[25];
    const float* dec_out   = (const float*)d_in[26];
    float* out = (float*)d_out;
    float* w = (float*)d_ws;

    // workspace layout (floats)
    size_t off = 0;
    float* f2     = w + off; off += (size_t)2 * S_ * 512;
    float* Ktab   = w + off; off += (size_t)2 * S_ * 512;
    float* Vtab   = w + off; off += (size_t)2 * S_ * 512;
    float* act    = w + off; off += (size_t)B_ * D_MODEL_;
    float* cat    = w + off; off += (size_t)B_ * 2560;
    float* a_a    = w + off; off += (size_t)B_ * REP_;
    float* a_o    = w + off; off += (size_t)B_ * REP_;
    float* qbuf   = w + off; off += (size_t)B_ * 512;
    float* o_attn = w + off; off += (size_t)B_ * 512;
    float* pre    = w + off; off += (size_t)B_ * 4096;
    float* trace  = w + off; off += (size_t)B_ * D_MODEL_ * M_;
    float* scbuf  = w + off; off += (size_t)16 * 128 * S_;
    float* predst = w + off; off += (size_t)T_ * PRED_N;     // (T, B*4096)
    float* certbf = w + off; off += (size_t)T_ * B_ * 2;
    ushort_t* s_actb = (ushort_t*)(w + off); off += (size_t)B_ * REP_ / 2;
    ushort_t* s_outb = (ushort_t*)(w + off); off += (size_t)B_ * REP_ / 2;
    __hip_bfloat16* Kb = (__hip_bfloat16*)(w + off); off += (size_t)S_ * 512;
    ushort_t* Pbuf  = (ushort_t*)(w + off); off += (size_t)8 * 128 * 4096 / 2;
    ushort_t* VT    = (ushort_t*)(w + off); off += (size_t)8 * 64 * 4096 / 2;
    ushort_t* WkT   = (ushort_t*)(w + off); off += (size_t)512 * 512 / 2;
    ushort_t* WvT   = (ushort_t*)(w + off); off += (size_t)512 * 512 / 2;
    ushort_t* WqT   = (ushort_t*)(w + off); off += (size_t)512 * REP_ / 2;
    ushort_t* WoT   = (ushort_t*)(w + off); off += (size_t)512 * 512 / 2;
    ushort_t* WsT   = (ushort_t*)(w + off); off += (size_t)4096 * 2560 / 2;
    ushort_t* WoutT = (ushort_t*)(w + off); off += (size_t)4096 * REP_ / 2;

    // ---- pre-loop ----
    feats_kernel<<<(2 * S_ * 512) / 256, 256, 0, stream>>>(emb, W_pos, b_pos, f2);
    init_act_kernel<<<(B_ * D_MODEL_) / 256, 256, 0, stream>>>(start_act, act, cat);
    init_trace_kernel<<<(B_ * D_MODEL_ * M_) / 256, 256, 0, stream>>>(start_tr, trace);

    transpose_bf16_kernel<<<dim3(512 / 32, 512 / 32), 256, 0, stream>>>(Wk, WkT, 512, 512);
    transpose_bf16_kernel<<<dim3(512 / 32, 512 / 32), 256, 0, stream>>>(Wv, WvT, 512, 512);
    transpose_bf16_kernel<<<dim3(512 / 32, REP_ / 32), 256, 0, stream>>>(Wq, WqT, REP_, 512);
    transpose_bf16_kernel<<<dim3(512 / 32, 512 / 32), 256, 0, stream>>>(Wo, WoT, 512, 512);
    transpose_bf16_kernel<<<dim3(4096 / 32, 2560 / 32), 256, 0, stream>>>(Ws, WsT, 2560, 4096);
    transpose_bf16_kernel<<<dim3(4096 / 32, REP_ / 32), 256, 0, stream>>>(Wout, WoutT, REP_, 4096);

    gemm_bf16<<<dim3(512 / 128, (2 * S_) / 64, 1), 256, 0, stream>>>(
        f2, 512, WkT, 512, bk, Ktab, 512, 2 * S_, 512, 512, 512);
    gemm_bf16<<<dim3(512 / 128, (2 * S_) / 64, 1), 256, 0, stream>>>(
        f2, 512, WvT, 512, bv, Vtab, 512, 2 * S_, 512, 512, 512);
    cast_bf16_kernel<<<(2 * S_ * 512 / 4) / 256, 256, 0, stream>>>(Ktab, Kb, 2 * S_ * 512);
    build_vt<<<(8 * 64 * 4096) / 256, 256, 0, stream>>>(Vtab, VT);

    // ---- T iterations ----
    for (int t = 0; t < T_; t++) {
        // sync action; y==8 block also inits qbuf=bq and pre=bs
        sync_kernel<<<dim3(B_, 9), 256, 0, stream>>>(
            act, a_a, dec_act, t, D_MODEL_ - NSY_, s_actb,
            qbuf, bq, 512, pre, bs, 4096);

        gemm_bb<<<dim3(512 / 128, 2, 13), 256, 0, stream>>>(
            s_actb, REP_, WqT, REP_, bq, qbuf, 512, B_, 512, REP_, 160);

        gemm_qk<<<dim3(S_ / 128, 2, 16), 256, 0, stream>>>(
            qbuf, (const ushort_t*)Kb, scbuf);
        attn_soft<<<B_ * H_, 256, 0, stream>>>(scbuf, tokens, Pbuf, o_attn, cat, bo);
        gemm_pv<<<dim3(2, 8, 8), 256, 0, stream>>>(Pbuf, VT, o_attn);

        gemm_bf16<<<dim3(512 / 128, 2, 8), 256, 0, stream>>>(
            o_attn, 512, WoT, 512, bo, cat, 2560, B_, 512, 512, 64);

        gemm_bf16<<<dim3(4096 / 128, 2, 8), 256, 0, stream>>>(
            cat, 2560, WsT, 2560, bs, pre, 4096, B_, 4096, 2560, 320);

        state_trace_kernel<<<B_ * 2, 256, 0, stream>>>(
            pre, ln_s_g, ln_s_b, trace, ln_n_g, ln_n_b, Wn, bn, temp, act, cat);

        // sync out; y==8 block inits predstage_t = bout
        float* predt = predst + (size_t)t * PRED_N;
        sync_kernel<<<dim3(B_, 9), 256, 0, stream>>>(
            act, a_o, dec_out, t, 0, s_outb,
            predt, bout, 4096, nullptr, nullptr, 0);

        gemm_bb<<<dim3(4096 / 128, 2, 5), 256, 0, stream>>>(
            s_outb, REP_, WoutT, REP_, bout, predt, 4096, B_, 4096, REP_, 416);

        ent_kernel<<<B_, 256, 0, stream>>>(predt, certbf + t * B_ * 2);
    }

    // one coalesced pass to the strided output layout
    finalize_kernel<<<PRED_N / 1024, 256, 0, stream>>>(predst, certbf, out);
}